// Round 9
// baseline (410.945 us; speedup 1.0000x reference)
//
#include <hip/hip_runtime.h>

#define BB 16
#define TT 12
#define NN 1024
#define DD 64
#define EE 32
#define MM (TT*NN)          // 12288 rows per batch
#define ROWS (BB*MM)        // 196608 total rows
#define CPB2N 48            // k2 blocks per batch
#define CPB4 48             // k4 blocks per batch
#define LN_EPS 1e-5f

typedef __attribute__((ext_vector_type(8))) short short8;
typedef __attribute__((ext_vector_type(4))) float f32x4;
typedef __attribute__((ext_vector_type(4))) int   int4v;

// pack two f32 -> one dword of 2 bf16 (RNE), low = a, high = b
__device__ __forceinline__ int cvt2(float a, float b){
  int r;
  asm("v_cvt_pk_bf16_f32 %0, %1, %2" : "=v"(r) : "v"(a), "v"(b));
  return r;
}
__device__ __forceinline__ unsigned short bf16of(float a){
  return (unsigned short)(cvt2(a, a) & 0xffff);
}
__device__ __forceinline__ float f32of(unsigned short h){
  return __builtin_bit_cast(float, (unsigned int)h << 16);
}
__device__ __forceinline__ float lo16f(int w){ return __builtin_bit_cast(float, (unsigned int)w << 16); }
__device__ __forceinline__ float hi16f(int w){ return __builtin_bit_cast(float, (unsigned int)w & 0xffff0000u); }

__device__ __forceinline__ short8 pack_hi8(const float* v){
  int4v w;
  w.x = cvt2(v[0], v[1]); w.y = cvt2(v[2], v[3]);
  w.z = cvt2(v[4], v[5]); w.w = cvt2(v[6], v[7]);
  return __builtin_bit_cast(short8, w);
}
__device__ __forceinline__ short8 pack_lo8(const float* v, short8 hi){
  const int4v wh = __builtin_bit_cast(int4v, hi);
  float r[8];
  r[0] = v[0] - lo16f(wh.x); r[1] = v[1] - hi16f(wh.x);
  r[2] = v[2] - lo16f(wh.y); r[3] = v[3] - hi16f(wh.y);
  r[4] = v[4] - lo16f(wh.z); r[5] = v[5] - hi16f(wh.z);
  r[6] = v[6] - lo16f(wh.w); r[7] = v[7] - hi16f(wh.w);
  return pack_hi8(r);
}

// ---------------- K1: fused STGCN via bf16 MFMA, 2 tiles (32 rows) per wave ----------------
__global__ __launch_bounds__(256, 1)
void k1_stgcn(const float* __restrict__ x,
              const float* __restrict__ W1, const float* __restrict__ b1,
              const float* __restrict__ W2, const float* __restrict__ b2,
              const float* __restrict__ lng, const float* __restrict__ lnb,
              float* __restrict__ out1)
{
  const int lane = threadIdx.x & 63;
  const int wid  = threadIdx.x >> 6;
  const int l15  = lane & 15;
  const int lg   = lane >> 4;
  const int k0   = lg * 8;

  short8 bw[2][4][2];
  const float* Wm[2] = {W1, W2};
  #pragma unroll
  for (int m = 0; m < 2; ++m)
    #pragma unroll
    for (int nt = 0; nt < 4; ++nt)
      #pragma unroll
      for (int kc = 0; kc < 2; ++kc){
        const float* src = Wm[m] + (size_t)(16*nt + l15)*DD + 32*kc + k0;
        const float4 p0 = *reinterpret_cast<const float4*>(src);
        const float4 p1 = *reinterpret_cast<const float4*>(src + 4);
        int4v w;
        w.x = cvt2(p0.x, p0.y); w.y = cvt2(p0.z, p0.w);
        w.z = cvt2(p1.x, p1.y); w.w = cvt2(p1.z, p1.w);
        bw[m][nt][kc] = __builtin_bit_cast(short8, w);
      }

  float b1c[4], b2c[4], gamc[4], betc[4];
  #pragma unroll
  for (int nt = 0; nt < 4; ++nt){
    b1c[nt]  = b1[l15 + 16*nt];
    b2c[nt]  = b2[l15 + 16*nt];
    gamc[nt] = lng[l15 + 16*nt];
    betc[nt] = lnb[l15 + 16*nt];
  }

  const int p  = blockIdx.x*4 + wid;   // pair id, exactly ROWS/32 = 6144 waves
  const int rA = p * 32;               // tile A rows rA..rA+15
  const int rB = rA + 16;              // tile B rows
  const int t  = (rA >> 10) % TT;      // pair never crosses a frame boundary

  // ---- all global loads up front (x is read-only here: hoisting is value-identical) ----
  const float* pcA = x + (size_t)(rA + l15)*DD + k0;
  const float* pcB = x + (size_t)(rB + l15)*DD + k0;
  float4 A00 = *reinterpret_cast<const float4*>(pcA);
  float4 A01 = *reinterpret_cast<const float4*>(pcA + 4);
  float4 A10 = *reinterpret_cast<const float4*>(pcA + 32);
  float4 A11 = *reinterpret_cast<const float4*>(pcA + 36);
  float4 B00 = *reinterpret_cast<const float4*>(pcB);
  float4 B01 = *reinterpret_cast<const float4*>(pcB + 4);
  float4 B10 = *reinterpret_cast<const float4*>(pcB + 32);
  float4 B11 = *reinterpret_cast<const float4*>(pcB + 36);
  if (t > 0){
    const float* ppA = pcA - (size_t)NN*DD;
    const float* ppB = pcB - (size_t)NN*DD;
    const float4 qA0 = *reinterpret_cast<const float4*>(ppA);
    const float4 qA1 = *reinterpret_cast<const float4*>(ppA + 4);
    const float4 qA2 = *reinterpret_cast<const float4*>(ppA + 32);
    const float4 qA3 = *reinterpret_cast<const float4*>(ppA + 36);
    const float4 qB0 = *reinterpret_cast<const float4*>(ppB);
    const float4 qB1 = *reinterpret_cast<const float4*>(ppB + 4);
    const float4 qB2 = *reinterpret_cast<const float4*>(ppB + 32);
    const float4 qB3 = *reinterpret_cast<const float4*>(ppB + 36);
    A00.x=0.5f*(A00.x+qA0.x); A00.y=0.5f*(A00.y+qA0.y); A00.z=0.5f*(A00.z+qA0.z); A00.w=0.5f*(A00.w+qA0.w);
    A01.x=0.5f*(A01.x+qA1.x); A01.y=0.5f*(A01.y+qA1.y); A01.z=0.5f*(A01.z+qA1.z); A01.w=0.5f*(A01.w+qA1.w);
    A10.x=0.5f*(A10.x+qA2.x); A10.y=0.5f*(A10.y+qA2.y); A10.z=0.5f*(A10.z+qA2.z); A10.w=0.5f*(A10.w+qA2.w);
    A11.x=0.5f*(A11.x+qA3.x); A11.y=0.5f*(A11.y+qA3.y); A11.z=0.5f*(A11.z+qA3.z); A11.w=0.5f*(A11.w+qA3.w);
    B00.x=0.5f*(B00.x+qB0.x); B00.y=0.5f*(B00.y+qB0.y); B00.z=0.5f*(B00.z+qB0.z); B00.w=0.5f*(B00.w+qB0.w);
    B01.x=0.5f*(B01.x+qB1.x); B01.y=0.5f*(B01.y+qB1.y); B01.z=0.5f*(B01.z+qB1.z); B01.w=0.5f*(B01.w+qB1.w);
    B10.x=0.5f*(B10.x+qB2.x); B10.y=0.5f*(B10.y+qB2.y); B10.z=0.5f*(B10.z+qB2.z); B10.w=0.5f*(B10.w+qB2.w);
    B11.x=0.5f*(B11.x+qB3.x); B11.y=0.5f*(B11.y+qB3.y); B11.z=0.5f*(B11.z+qB3.z); B11.w=0.5f*(B11.w+qB3.w);
  } else {
    A00.x*=0.5f;A00.y*=0.5f;A00.z*=0.5f;A00.w*=0.5f;
    A01.x*=0.5f;A01.y*=0.5f;A01.z*=0.5f;A01.w*=0.5f;
    A10.x*=0.5f;A10.y*=0.5f;A10.z*=0.5f;A10.w*=0.5f;
    A11.x*=0.5f;A11.y*=0.5f;A11.z*=0.5f;A11.w*=0.5f;
    B00.x*=0.5f;B00.y*=0.5f;B00.z*=0.5f;B00.w*=0.5f;
    B01.x*=0.5f;B01.y*=0.5f;B01.z*=0.5f;B01.w*=0.5f;
    B10.x*=0.5f;B10.y*=0.5f;B10.z*=0.5f;B10.w*=0.5f;
    B11.x*=0.5f;B11.y*=0.5f;B11.z*=0.5f;B11.w*=0.5f;
  }
  float epiA[4][4], epiB[4][4];
  #pragma unroll
  for (int q = 0; q < 4; ++q){
    const float* prA = x + (size_t)(rA + 4*lg + q)*DD + l15;
    const float* prB = x + (size_t)(rB + 4*lg + q)*DD + l15;
    #pragma unroll
    for (int nt = 0; nt < 4; ++nt){ epiA[q][nt] = prA[16*nt]; epiB[q][nt] = prB[16*nt]; }
  }

  short8 afA[2], afB[2];
  {
    int4v w;
    w.x = cvt2(A00.x, A00.y); w.y = cvt2(A00.z, A00.w);
    w.z = cvt2(A01.x, A01.y); w.w = cvt2(A01.z, A01.w);
    afA[0] = __builtin_bit_cast(short8, w);
    w.x = cvt2(A10.x, A10.y); w.y = cvt2(A10.z, A10.w);
    w.z = cvt2(A11.x, A11.y); w.w = cvt2(A11.z, A11.w);
    afA[1] = __builtin_bit_cast(short8, w);
    w.x = cvt2(B00.x, B00.y); w.y = cvt2(B00.z, B00.w);
    w.z = cvt2(B01.x, B01.y); w.w = cvt2(B01.z, B01.w);
    afB[0] = __builtin_bit_cast(short8, w);
    w.x = cvt2(B10.x, B10.y); w.y = cvt2(B10.z, B10.w);
    w.z = cvt2(B11.x, B11.y); w.w = cvt2(B11.z, B11.w);
    afB[1] = __builtin_bit_cast(short8, w);
  }

  f32x4 accA[2][4], accB[2][4];
  #pragma unroll
  for (int m = 0; m < 2; ++m)
    #pragma unroll
    for (int nt = 0; nt < 4; ++nt){
      accA[m][nt] = (f32x4){0.f,0.f,0.f,0.f};
      accB[m][nt] = (f32x4){0.f,0.f,0.f,0.f};
    }

  #pragma unroll
  for (int kc = 0; kc < 2; ++kc){
    #pragma unroll
    for (int nt = 0; nt < 4; ++nt){
      accA[0][nt] = __builtin_amdgcn_mfma_f32_16x16x32_bf16(afA[kc], bw[0][nt][kc], accA[0][nt], 0, 0, 0);
      accA[1][nt] = __builtin_amdgcn_mfma_f32_16x16x32_bf16(afA[kc], bw[1][nt][kc], accA[1][nt], 0, 0, 0);
      accB[0][nt] = __builtin_amdgcn_mfma_f32_16x16x32_bf16(afB[kc], bw[0][nt][kc], accB[0][nt], 0, 0, 0);
      accB[1][nt] = __builtin_amdgcn_mfma_f32_16x16x32_bf16(afB[kc], bw[1][nt][kc], accB[1][nt], 0, 0, 0);
    }
  }

  #pragma unroll
  for (int q = 0; q < 4; ++q){
    const int rowA = rA + 4*lg + q;
    const int rowB = rB + 4*lg + q;
    float sA[4], sB[4];
    float rsA = 0.f, rsB = 0.f;
    #pragma unroll
    for (int nt = 0; nt < 4; ++nt){
      const float g1A = accA[0][nt][q] + b1c[nt];
      const float g2A = accA[1][nt][q] + b2c[nt];
      sA[nt] = fmaxf(g1A*g2A, 0.f) + g1A + epiA[q][nt];
      rsA += sA[nt];
      const float g1B = accB[0][nt][q] + b1c[nt];
      const float g2B = accB[1][nt][q] + b2c[nt];
      sB[nt] = fmaxf(g1B*g2B, 0.f) + g1B + epiB[q][nt];
      rsB += sB[nt];
    }
    #pragma unroll
    for (int off = 8; off; off >>= 1){ rsA += __shfl_xor(rsA, off); rsB += __shfl_xor(rsB, off); }
    const float meanA = rsA * (1.f/DD);
    const float meanB = rsB * (1.f/DD);
    float dA[4], dB[4]; float vsA = 0.f, vsB = 0.f;
    #pragma unroll
    for (int nt = 0; nt < 4; ++nt){
      dA[nt] = sA[nt] - meanA; vsA = fmaf(dA[nt], dA[nt], vsA);
      dB[nt] = sB[nt] - meanB; vsB = fmaf(dB[nt], dB[nt], vsB);
    }
    #pragma unroll
    for (int off = 8; off; off >>= 1){ vsA += __shfl_xor(vsA, off); vsB += __shfl_xor(vsB, off); }
    const float invA = rsqrtf(vsA * (1.f/DD) + LN_EPS);
    const float invB = rsqrtf(vsB * (1.f/DD) + LN_EPS);
    #pragma unroll
    for (int nt = 0; nt < 4; ++nt){
      out1[(size_t)rowA*DD + l15 + 16*nt] = dA[nt]*invA*gamc[nt] + betc[nt];
      out1[(size_t)rowB*DD + l15 + 16*nt] = dB[nt]*invB*gamc[nt] + betc[nt];
    }
  }
}

// ---------------- K2: full-MFMA hyper stage 1 (verbatim round 7) ----------------
__global__ __launch_bounds__(256, 3)
void k2_hyper1(const float* __restrict__ x, const float* __restrict__ clf,
               unsigned short* __restrict__ assign_hi, unsigned short* __restrict__ assign_lo,
               float* __restrict__ hf_part)
{
  __shared__ __align__(16) float lbuf[4224];   // union: amat 4x[32][33] | red 2x[32][65]
  const int lane = threadIdx.x & 63;
  const int wid  = threadIdx.x >> 6;
  const int l15  = lane & 15;
  const int lg   = lane >> 4;
  const int b    = blockIdx.x / CPB2N;
  const int blk  = blockIdx.x % CPB2N;
  float* amat = lbuf + wid*1056;               // [32][33] f32 per wave

  short8 bch[2][2], bcl[2][2];
  #pragma unroll
  for (int kc = 0; kc < 2; ++kc)
    #pragma unroll
    for (int nt = 0; nt < 2; ++nt){
      float v[8];
      #pragma unroll
      for (int j = 0; j < 8; ++j)
        v[j] = clf[(size_t)(32*kc + 8*lg + j)*EE + 16*nt + l15];
      bch[kc][nt] = pack_hi8(v);
      bcl[kc][nt] = pack_lo8(v, bch[kc][nt]);
    }

  f32x4 acc2[2][4];
  #pragma unroll
  for (int et = 0; et < 2; ++et)
    #pragma unroll
    for (int dt = 0; dt < 4; ++dt) acc2[et][dt] = (f32x4){0.f,0.f,0.f,0.f};

  const int wslot = blk*4 + wid;               // 0..191
  #pragma unroll 1
  for (int s = 0; s < 2; ++s){
    const int c = wslot + s*192;
    const size_t grb = (size_t)b*MM + (size_t)c*32;

    #pragma unroll 1
    for (int h = 0; h < 2; ++h){
      short8 axh[2], axl[2];
      #pragma unroll
      for (int kc = 0; kc < 2; ++kc){
        const float* p = x + (grb + 16*h + l15)*DD + 32*kc + 8*lg;
        float v[8];
        const float4 p0 = *reinterpret_cast<const float4*>(p);
        const float4 p1 = *reinterpret_cast<const float4*>(p + 4);
        v[0]=p0.x; v[1]=p0.y; v[2]=p0.z; v[3]=p0.w;
        v[4]=p1.x; v[5]=p1.y; v[6]=p1.z; v[7]=p1.w;
        axh[kc] = pack_hi8(v); axl[kc] = pack_lo8(v, axh[kc]);
      }
      f32x4 accL[2] = {(f32x4){0.f,0.f,0.f,0.f},(f32x4){0.f,0.f,0.f,0.f}};
      #pragma unroll
      for (int kc = 0; kc < 2; ++kc)
        #pragma unroll
        for (int nt = 0; nt < 2; ++nt){
          accL[nt] = __builtin_amdgcn_mfma_f32_16x16x32_bf16(axh[kc], bch[kc][nt], accL[nt], 0, 0, 0);
          accL[nt] = __builtin_amdgcn_mfma_f32_16x16x32_bf16(axh[kc], bcl[kc][nt], accL[nt], 0, 0, 0);
          accL[nt] = __builtin_amdgcn_mfma_f32_16x16x32_bf16(axl[kc], bch[kc][nt], accL[nt], 0, 0, 0);
        }
      #pragma unroll
      for (int q = 0; q < 4; ++q){
        const float l0 = accL[0][q], l1 = accL[1][q];
        float mx = fmaxf(l0, l1);
        #pragma unroll
        for (int off = 8; off; off >>= 1) mx = fmaxf(mx, __shfl_xor(mx, off));
        const float e0 = expf(l0 - mx), e1 = expf(l1 - mx);
        float sm = e0 + e1;
        #pragma unroll
        for (int off = 8; off; off >>= 1) sm += __shfl_xor(sm, off);
        const float inv = 1.f / sm;
        const float a0 = e0*inv, a1 = e1*inv;
        const int rloc = 16*h + 4*lg + q;
        const size_t row = grb + rloc;
        const unsigned short h0 = bf16of(a0);
        const unsigned short h1 = bf16of(a1);
        assign_hi[row*EE + l15]      = h0;
        assign_hi[row*EE + 16 + l15] = h1;
        assign_lo[row*EE + l15]      = bf16of(a0 - f32of(h0));
        assign_lo[row*EE + 16 + l15] = bf16of(a1 - f32of(h1));
        amat[rloc*33 + l15]      = a0;
        amat[rloc*33 + 16 + l15] = a1;
      }
    }
    __builtin_amdgcn_wave_barrier();
    short8 a2h[2], a2l[2];
    #pragma unroll
    for (int et = 0; et < 2; ++et){
      float v[8];
      #pragma unroll
      for (int j = 0; j < 8; ++j)
        v[j] = amat[(8*lg + j)*33 + 16*et + l15];
      a2h[et] = pack_hi8(v); a2l[et] = pack_lo8(v, a2h[et]);
    }
    #pragma unroll
    for (int dt = 0; dt < 4; ++dt){
      float v[8];
      #pragma unroll
      for (int j = 0; j < 8; ++j)
        v[j] = x[(grb + 8*lg + j)*DD + 16*dt + l15];
      const short8 b2 = pack_hi8(v);
      #pragma unroll
      for (int et = 0; et < 2; ++et){
        acc2[et][dt] = __builtin_amdgcn_mfma_f32_16x16x32_bf16(a2h[et], b2, acc2[et][dt], 0, 0, 0);
        acc2[et][dt] = __builtin_amdgcn_mfma_f32_16x16x32_bf16(a2l[et], b2, acc2[et][dt], 0, 0, 0);
      }
    }
    __builtin_amdgcn_wave_barrier();
  }

  __syncthreads();
  float* red = lbuf;
  if (wid < 2){
    #pragma unroll
    for (int et = 0; et < 2; ++et)
      #pragma unroll
      for (int dt = 0; dt < 4; ++dt)
        #pragma unroll
        for (int q = 0; q < 4; ++q)
          red[wid*2080 + (16*et + 4*lg + q)*65 + 16*dt + l15] = acc2[et][dt][q];
  }
  __syncthreads();
  if (wid >= 2){
    #pragma unroll
    for (int et = 0; et < 2; ++et)
      #pragma unroll
      for (int dt = 0; dt < 4; ++dt)
        #pragma unroll
        for (int q = 0; q < 4; ++q)
          red[(wid-2)*2080 + (16*et + 4*lg + q)*65 + 16*dt + l15] += acc2[et][dt][q];
  }
  __syncthreads();
  float* dst = hf_part + ((size_t)b*CPB2N + blk)*(EE*DD);
  for (int i = threadIdx.x; i < EE*DD; i += 256){
    const int e = i >> 6, d = i & 63;
    dst[i] = red[e*65 + d] + red[2080 + e*65 + d];
  }
}

// ---------------- K3: sum hf_part slots; ho = relu(em @ hf) + hf; emit transposed bf16 hi/lo ----------------
__global__ void k3_edge(const float* __restrict__ hf_part, const float* __restrict__ em,
                        unsigned short* __restrict__ ho_hi, unsigned short* __restrict__ ho_lo)
{
  __shared__ float ems[EE*EE];
  __shared__ float hfs[EE*DD];
  const int b = blockIdx.x;
  const int tid = threadIdx.x;
  for (int i = tid; i < EE*EE; i += 256) ems[i] = em[i];
  for (int i = tid; i < EE*DD; i += 256){
    const float* p = hf_part + (size_t)b*CPB2N*(EE*DD) + i;
    float s0=0.f, s1=0.f, s2=0.f, s3=0.f;
    #pragma unroll
    for (int k = 0; k < CPB2N; k += 4){
      s0 += p[(size_t)(k+0)*EE*DD]; s1 += p[(size_t)(k+1)*EE*DD];
      s2 += p[(size_t)(k+2)*EE*DD]; s3 += p[(size_t)(k+3)*EE*DD];
    }
    hfs[i] = (s0+s1)+(s2+s3);
  }
  __syncthreads();
  for (int i = tid; i < EE*DD; i += 256){
    const int e = i >> 6, d = i & 63;
    float acc = 0.f;
    #pragma unroll
    for (int f = 0; f < EE; ++f) acc = fmaf(ems[e*EE+f], hfs[f*DD+d], acc);
    const float v = fmaxf(acc, 0.f) + hfs[e*DD+d];
    const unsigned short hi = bf16of(v);
    const unsigned short lo = bf16of(v - f32of(hi));
    ho_hi[((size_t)b*DD + d)*EE + e] = hi;
    ho_lo[((size_t)b*DD + d)*EE + e] = lo;
  }
}

// ---------------- K4: y = relu(assign @ ho) via split-MFMA, 2 tiles per iter ----------------
__global__ __launch_bounds__(256, 2)
void k4_combine(const float* __restrict__ x, const float* __restrict__ out1,
                const unsigned short* __restrict__ assign_hi,
                const unsigned short* __restrict__ assign_lo,
                const unsigned short* __restrict__ ho_hi,
                const unsigned short* __restrict__ ho_lo,
                const float* __restrict__ hg, const float* __restrict__ hb,
                float* __restrict__ xout)
{
  const int lane = threadIdx.x & 63;
  const int wid  = threadIdx.x >> 6;
  const int b    = blockIdx.x / CPB4;
  const int blk  = blockIdx.x % CPB4;
  const int l15  = lane & 15;
  const int lg   = lane >> 4;

  short8 bwh[4], bwl[4];
  #pragma unroll
  for (int nt = 0; nt < 4; ++nt){
    const size_t off = ((size_t)b*DD + l15 + 16*nt)*EE + 8*lg;
    bwh[nt] = *reinterpret_cast<const short8*>(ho_hi + off);
    bwl[nt] = *reinterpret_cast<const short8*>(ho_lo + off);
  }

  float gamc[4], betc[4];
  #pragma unroll
  for (int nt = 0; nt < 4; ++nt){
    gamc[nt] = hg[l15 + 16*nt];
    betc[nt] = hb[l15 + 16*nt];
  }

  const int ppb = MM / 32;              // 384 pairs per batch
  for (int pp = blk*4 + wid; pp < ppb; pp += CPB4*4){
    const size_t rA = (size_t)b*MM + (size_t)pp*32;
    const size_t rB = rA + 16;

    const short8 afhA = *reinterpret_cast<const short8*>(assign_hi + (rA + l15)*EE + 8*lg);
    const short8 aflA = *reinterpret_cast<const short8*>(assign_lo + (rA + l15)*EE + 8*lg);
    const short8 afhB = *reinterpret_cast<const short8*>(assign_hi + (rB + l15)*EE + 8*lg);
    const short8 aflB = *reinterpret_cast<const short8*>(assign_lo + (rB + l15)*EE + 8*lg);

    // hoisted epilogue loads
    float epxA[4][4], epoA[4][4], epxB[4][4], epoB[4][4];
    #pragma unroll
    for (int q = 0; q < 4; ++q){
      const float* pxA = x    + (rA + 4*lg + q)*DD + l15;
      const float* poA = out1 + (rA + 4*lg + q)*DD + l15;
      const float* pxB = x    + (rB + 4*lg + q)*DD + l15;
      const float* poB = out1 + (rB + 4*lg + q)*DD + l15;
      #pragma unroll
      for (int nt = 0; nt < 4; ++nt){
        epxA[q][nt] = pxA[16*nt]; epoA[q][nt] = poA[16*nt];
        epxB[q][nt] = pxB[16*nt]; epoB[q][nt] = poB[16*nt];
      }
    }

    f32x4 accA[4], accB[4];
    #pragma unroll
    for (int nt = 0; nt < 4; ++nt){ accA[nt] = (f32x4){0.f,0.f,0.f,0.f}; accB[nt] = (f32x4){0.f,0.f,0.f,0.f}; }
    #pragma unroll
    for (int nt = 0; nt < 4; ++nt){
      accA[nt] = __builtin_amdgcn_mfma_f32_16x16x32_bf16(afhA, bwh[nt], accA[nt], 0, 0, 0);
      accA[nt] = __builtin_amdgcn_mfma_f32_16x16x32_bf16(afhA, bwl[nt], accA[nt], 0, 0, 0);
      accA[nt] = __builtin_amdgcn_mfma_f32_16x16x32_bf16(aflA, bwh[nt], accA[nt], 0, 0, 0);
      accB[nt] = __builtin_amdgcn_mfma_f32_16x16x32_bf16(afhB, bwh[nt], accB[nt], 0, 0, 0);
      accB[nt] = __builtin_amdgcn_mfma_f32_16x16x32_bf16(afhB, bwl[nt], accB[nt], 0, 0, 0);
      accB[nt] = __builtin_amdgcn_mfma_f32_16x16x32_bf16(aflB, bwh[nt], accB[nt], 0, 0, 0);
    }

    #pragma unroll
    for (int q = 0; q < 4; ++q){
      const size_t rowA = rA + 4*lg + q;
      const size_t rowB = rB + 4*lg + q;
      float sA[4], sB[4];
      float rsA = 0.f, rsB = 0.f;
      #pragma unroll
      for (int nt = 0; nt < 4; ++nt){
        sA[nt] = fmaxf(accA[nt][q], 0.f) + epxA[q][nt]; rsA += sA[nt];
        sB[nt] = fmaxf(accB[nt][q], 0.f) + epxB[q][nt]; rsB += sB[nt];
      }
      #pragma unroll
      for (int off = 8; off; off >>= 1){ rsA += __shfl_xor(rsA, off); rsB += __shfl_xor(rsB, off); }
      const float meanA = rsA * (1.f/DD);
      const float meanB = rsB * (1.f/DD);
      float dA[4], dB[4]; float vsA = 0.f, vsB = 0.f;
      #pragma unroll
      for (int nt = 0; nt < 4; ++nt){
        dA[nt] = sA[nt] - meanA; vsA = fmaf(dA[nt], dA[nt], vsA);
        dB[nt] = sB[nt] - meanB; vsB = fmaf(dB[nt], dB[nt], vsB);
      }
      #pragma unroll
      for (int off = 8; off; off >>= 1){ vsA += __shfl_xor(vsA, off); vsB += __shfl_xor(vsB, off); }
      const float invA = rsqrtf(vsA * (1.f/DD) + LN_EPS);
      const float invB = rsqrtf(vsB * (1.f/DD) + LN_EPS);
      #pragma unroll
      for (int nt = 0; nt < 4; ++nt){
        const float o2A = dA[nt]*invA*gamc[nt] + betc[nt];
        const float o2B = dB[nt]*invB*gamc[nt] + betc[nt];
        xout[rowA*DD + l15 + 16*nt] = 0.5f*(epoA[q][nt] + o2A);
        xout[rowB*DD + l15 + 16*nt] = 0.5f*(epoB[q][nt] + o2B);
      }
    }
  }
}

extern "C" void kernel_launch(void* const* d_in, const int* in_sizes, int n_in,
                              void* d_out, int out_size, void* d_ws, size_t ws_size,
                              hipStream_t stream)
{
  (void)in_sizes; (void)n_in; (void)out_size; (void)ws_size;
  const float* x0  = (const float*)d_in[0];
  const float* W1  = (const float*)d_in[1];
  const float* b1  = (const float*)d_in[2];
  const float* W2  = (const float*)d_in[3];
  const float* b2  = (const float*)d_in[4];
  const float* lng = (const float*)d_in[5];
  const float* lnb = (const float*)d_in[6];
  const float* clf = (const float*)d_in[7];
  const float* em  = (const float*)d_in[8];
  const float* hg  = (const float*)d_in[9];
  const float* hb  = (const float*)d_in[10];
  float* out = (float*)d_out;

  // workspace: x ping f32 | hf_part f32 [BB][CPB2N][EE*DD] | assign hi/lo bf16 | ho hi/lo bf16
  float* ws_x = (float*)d_ws;
  float* hf_part = ws_x + (size_t)ROWS*DD;
  unsigned short* assign_hi = (unsigned short*)(hf_part + (size_t)BB*CPB2N*EE*DD);
  unsigned short* assign_lo = assign_hi + (size_t)ROWS*EE;
  unsigned short* ho_hi     = assign_lo + (size_t)ROWS*EE;
  unsigned short* ho_lo     = ho_hi + (size_t)BB*DD*EE;

  for (int i = 0; i < 3; ++i){
    const float* xin = (i == 0) ? x0 : ws_x;
    float* xout = (i == 2) ? out : ws_x;
    k1_stgcn<<<1536, 256, 0, stream>>>(xin, W1 + i*DD*DD, b1 + i*DD,
                                       W2 + i*DD*DD, b2 + i*DD,
                                       lng + i*DD, lnb + i*DD, out);
    k2_hyper1<<<BB*CPB2N, 256, 0, stream>>>(xin, clf, assign_hi, assign_lo, hf_part);
    k3_edge<<<BB, 256, 0, stream>>>(hf_part, em, ho_hi, ho_lo);
    k4_combine<<<BB*CPB4, 256, 0, stream>>>(xin, out, assign_hi, assign_lo, ho_hi, ho_lo, hg, hb, xout);
  }
}

// Round 12
// 325.235 us; speedup vs baseline: 1.2635x; 1.2635x over previous
//
#include <hip/hip_runtime.h>

#define BB 16
#define TT 12
#define NN 1024
#define DD 64
#define EE 32
#define MM (TT*NN)          // 12288 rows per batch
#define ROWS (BB*MM)        // 196608 total rows
#define CPB2N 48            // k2 blocks per batch
#define CPB4 48             // k14 blocks per batch
#define LN_EPS 1e-5f

typedef __attribute__((ext_vector_type(8))) short short8;
typedef __attribute__((ext_vector_type(4))) float f32x4;
typedef __attribute__((ext_vector_type(4))) int   int4v;

// pack two f32 -> one dword of 2 bf16 (RNE), low = a, high = b
__device__ __forceinline__ int cvt2(float a, float b){
  int r;
  asm("v_cvt_pk_bf16_f32 %0, %1, %2" : "=v"(r) : "v"(a), "v"(b));
  return r;
}
__device__ __forceinline__ unsigned short bf16of(float a){
  return (unsigned short)(cvt2(a, a) & 0xffff);
}
__device__ __forceinline__ float f32of(unsigned short h){
  return __builtin_bit_cast(float, (unsigned int)h << 16);
}
__device__ __forceinline__ float lo16f(int w){ return __builtin_bit_cast(float, (unsigned int)w << 16); }
__device__ __forceinline__ float hi16f(int w){ return __builtin_bit_cast(float, (unsigned int)w & 0xffff0000u); }

__device__ __forceinline__ short8 pack_hi8(const float* v){
  int4v w;
  w.x = cvt2(v[0], v[1]); w.y = cvt2(v[2], v[3]);
  w.z = cvt2(v[4], v[5]); w.w = cvt2(v[6], v[7]);
  return __builtin_bit_cast(short8, w);
}
__device__ __forceinline__ short8 pack_lo8(const float* v, short8 hi){
  const int4v wh = __builtin_bit_cast(int4v, hi);
  float r[8];
  r[0] = v[0] - lo16f(wh.x); r[1] = v[1] - hi16f(wh.x);
  r[2] = v[2] - lo16f(wh.y); r[3] = v[3] - hi16f(wh.y);
  r[4] = v[4] - lo16f(wh.z); r[5] = v[5] - hi16f(wh.z);
  r[6] = v[6] - lo16f(wh.w); r[7] = v[7] - hi16f(wh.w);
  return pack_hi8(r);
}

// ---------------- K2: full-MFMA hyper stage 1 (verbatim round 7, PASSING) ----------------
__global__ __launch_bounds__(256, 3)
void k2_hyper1(const float* __restrict__ x, const float* __restrict__ clf,
               unsigned short* __restrict__ assign_hi, unsigned short* __restrict__ assign_lo,
               float* __restrict__ hf_part)
{
  __shared__ __align__(16) float lbuf[4224];   // union: amat 4x[32][33] | red 2x[32][65]
  const int lane = threadIdx.x & 63;
  const int wid  = threadIdx.x >> 6;
  const int l15  = lane & 15;
  const int lg   = lane >> 4;
  const int b    = blockIdx.x / CPB2N;
  const int blk  = blockIdx.x % CPB2N;
  float* amat = lbuf + wid*1056;               // [32][33] f32 per wave

  short8 bch[2][2], bcl[2][2];
  #pragma unroll
  for (int kc = 0; kc < 2; ++kc)
    #pragma unroll
    for (int nt = 0; nt < 2; ++nt){
      float v[8];
      #pragma unroll
      for (int j = 0; j < 8; ++j)
        v[j] = clf[(size_t)(32*kc + 8*lg + j)*EE + 16*nt + l15];
      bch[kc][nt] = pack_hi8(v);
      bcl[kc][nt] = pack_lo8(v, bch[kc][nt]);
    }

  f32x4 acc2[2][4];
  #pragma unroll
  for (int et = 0; et < 2; ++et)
    #pragma unroll
    for (int dt = 0; dt < 4; ++dt) acc2[et][dt] = (f32x4){0.f,0.f,0.f,0.f};

  const int wslot = blk*4 + wid;               // 0..191
  #pragma unroll 1
  for (int s = 0; s < 2; ++s){
    const int c = wslot + s*192;
    const size_t grb = (size_t)b*MM + (size_t)c*32;

    #pragma unroll 1
    for (int h = 0; h < 2; ++h){
      short8 axh[2], axl[2];
      #pragma unroll
      for (int kc = 0; kc < 2; ++kc){
        const float* p = x + (grb + 16*h + l15)*DD + 32*kc + 8*lg;
        float v[8];
        const float4 p0 = *reinterpret_cast<const float4*>(p);
        const float4 p1 = *reinterpret_cast<const float4*>(p + 4);
        v[0]=p0.x; v[1]=p0.y; v[2]=p0.z; v[3]=p0.w;
        v[4]=p1.x; v[5]=p1.y; v[6]=p1.z; v[7]=p1.w;
        axh[kc] = pack_hi8(v); axl[kc] = pack_lo8(v, axh[kc]);
      }
      f32x4 accL[2] = {(f32x4){0.f,0.f,0.f,0.f},(f32x4){0.f,0.f,0.f,0.f}};
      #pragma unroll
      for (int kc = 0; kc < 2; ++kc)
        #pragma unroll
        for (int nt = 0; nt < 2; ++nt){
          accL[nt] = __builtin_amdgcn_mfma_f32_16x16x32_bf16(axh[kc], bch[kc][nt], accL[nt], 0, 0, 0);
          accL[nt] = __builtin_amdgcn_mfma_f32_16x16x32_bf16(axh[kc], bcl[kc][nt], accL[nt], 0, 0, 0);
          accL[nt] = __builtin_amdgcn_mfma_f32_16x16x32_bf16(axl[kc], bch[kc][nt], accL[nt], 0, 0, 0);
        }
      #pragma unroll
      for (int q = 0; q < 4; ++q){
        const float l0 = accL[0][q], l1 = accL[1][q];
        float mx = fmaxf(l0, l1);
        #pragma unroll
        for (int off = 8; off; off >>= 1) mx = fmaxf(mx, __shfl_xor(mx, off));
        const float e0 = expf(l0 - mx), e1 = expf(l1 - mx);
        float sm = e0 + e1;
        #pragma unroll
        for (int off = 8; off; off >>= 1) sm += __shfl_xor(sm, off);
        const float inv = 1.f / sm;
        const float a0 = e0*inv, a1 = e1*inv;
        const int rloc = 16*h + 4*lg + q;
        const size_t row = grb + rloc;
        const unsigned short h0 = bf16of(a0);
        const unsigned short h1 = bf16of(a1);
        assign_hi[row*EE + l15]      = h0;
        assign_hi[row*EE + 16 + l15] = h1;
        assign_lo[row*EE + l15]      = bf16of(a0 - f32of(h0));
        assign_lo[row*EE + 16 + l15] = bf16of(a1 - f32of(h1));
        amat[rloc*33 + l15]      = a0;
        amat[rloc*33 + 16 + l15] = a1;
      }
    }
    __builtin_amdgcn_wave_barrier();
    short8 a2h[2], a2l[2];
    #pragma unroll
    for (int et = 0; et < 2; ++et){
      float v[8];
      #pragma unroll
      for (int j = 0; j < 8; ++j)
        v[j] = amat[(8*lg + j)*33 + 16*et + l15];
      a2h[et] = pack_hi8(v); a2l[et] = pack_lo8(v, a2h[et]);
    }
    #pragma unroll
    for (int dt = 0; dt < 4; ++dt){
      float v[8];
      #pragma unroll
      for (int j = 0; j < 8; ++j)
        v[j] = x[(grb + 8*lg + j)*DD + 16*dt + l15];
      const short8 b2 = pack_hi8(v);
      #pragma unroll
      for (int et = 0; et < 2; ++et){
        acc2[et][dt] = __builtin_amdgcn_mfma_f32_16x16x32_bf16(a2h[et], b2, acc2[et][dt], 0, 0, 0);
        acc2[et][dt] = __builtin_amdgcn_mfma_f32_16x16x32_bf16(a2l[et], b2, acc2[et][dt], 0, 0, 0);
      }
    }
    __builtin_amdgcn_wave_barrier();
  }

  __syncthreads();
  float* red = lbuf;
  if (wid < 2){
    #pragma unroll
    for (int et = 0; et < 2; ++et)
      #pragma unroll
      for (int dt = 0; dt < 4; ++dt)
        #pragma unroll
        for (int q = 0; q < 4; ++q)
          red[wid*2080 + (16*et + 4*lg + q)*65 + 16*dt + l15] = acc2[et][dt][q];
  }
  __syncthreads();
  if (wid >= 2){
    #pragma unroll
    for (int et = 0; et < 2; ++et)
      #pragma unroll
      for (int dt = 0; dt < 4; ++dt)
        #pragma unroll
        for (int q = 0; q < 4; ++q)
          red[(wid-2)*2080 + (16*et + 4*lg + q)*65 + 16*dt + l15] += acc2[et][dt][q];
  }
  __syncthreads();
  float* dst = hf_part + ((size_t)b*CPB2N + blk)*(EE*DD);
  for (int i = threadIdx.x; i < EE*DD; i += 256){
    const int e = i >> 6, d = i & 63;
    dst[i] = red[e*65 + d] + red[2080 + e*65 + d];
  }
}

// ---------------- K3: sum hf_part slots; ho = relu(em @ hf) + hf; emit transposed bf16 hi/lo ----------------
__global__ void k3_edge(const float* __restrict__ hf_part, const float* __restrict__ em,
                        unsigned short* __restrict__ ho_hi, unsigned short* __restrict__ ho_lo)
{
  __shared__ float ems[EE*EE];
  __shared__ float hfs[EE*DD];
  const int b = blockIdx.x;
  const int tid = threadIdx.x;
  for (int i = tid; i < EE*EE; i += 256) ems[i] = em[i];
  for (int i = tid; i < EE*DD; i += 256){
    const float* p = hf_part + (size_t)b*CPB2N*(EE*DD) + i;
    float s0=0.f, s1=0.f, s2=0.f, s3=0.f;
    #pragma unroll
    for (int k = 0; k < CPB2N; k += 4){
      s0 += p[(size_t)(k+0)*EE*DD]; s1 += p[(size_t)(k+1)*EE*DD];
      s2 += p[(size_t)(k+2)*EE*DD]; s3 += p[(size_t)(k+3)*EE*DD];
    }
    hfs[i] = (s0+s1)+(s2+s3);
  }
  __syncthreads();
  for (int i = tid; i < EE*DD; i += 256){
    const int e = i >> 6, d = i & 63;
    float acc = 0.f;
    #pragma unroll
    for (int f = 0; f < EE; ++f) acc = fmaf(ems[e*EE+f], hfs[f*DD+d], acc);
    const float v = fmaxf(acc, 0.f) + hfs[e*DD+d];
    const unsigned short hi = bf16of(v);
    const unsigned short lo = bf16of(v - f32of(hi));
    ho_hi[((size_t)b*DD + d)*EE + e] = hi;
    ho_lo[((size_t)b*DD + d)*EE + e] = lo;
  }
}

// ---------------- K14: fused STGCN + hyper-combine per tile (no out1 buffer) ----------------
// REQUIRES xin != xout (launcher ping-pongs): reads x[t-1] rows cross-tile.
__global__ __launch_bounds__(256, 2)
void k14_fused(const float* __restrict__ x,
               const float* __restrict__ W1, const float* __restrict__ b1,
               const float* __restrict__ W2, const float* __restrict__ b2,
               const float* __restrict__ lng, const float* __restrict__ lnb,
               const unsigned short* __restrict__ assign_hi,
               const unsigned short* __restrict__ assign_lo,
               const unsigned short* __restrict__ ho_hi,
               const unsigned short* __restrict__ ho_lo,
               const float* __restrict__ hg, const float* __restrict__ hb,
               float* __restrict__ xout)
{
  const int lane = threadIdx.x & 63;
  const int wid  = threadIdx.x >> 6;
  const int b    = blockIdx.x / CPB4;
  const int blk  = blockIdx.x % CPB4;
  const int l15  = lane & 15;
  const int lg   = lane >> 4;
  const int k0   = lg * 8;

  // W fragments (k1 part)
  short8 bw[2][4][2];
  const float* Wm[2] = {W1, W2};
  #pragma unroll
  for (int m = 0; m < 2; ++m)
    #pragma unroll
    for (int nt = 0; nt < 4; ++nt)
      #pragma unroll
      for (int kc = 0; kc < 2; ++kc){
        const float* src = Wm[m] + (size_t)(16*nt + l15)*DD + 32*kc + k0;
        const float4 p0 = *reinterpret_cast<const float4*>(src);
        const float4 p1 = *reinterpret_cast<const float4*>(src + 4);
        int4v w;
        w.x = cvt2(p0.x, p0.y); w.y = cvt2(p0.z, p0.w);
        w.z = cvt2(p1.x, p1.y); w.w = cvt2(p1.z, p1.w);
        bw[m][nt][kc] = __builtin_bit_cast(short8, w);
      }

  // ho fragments (k4 part, per batch)
  short8 bwh[4], bwl[4];
  #pragma unroll
  for (int nt = 0; nt < 4; ++nt){
    const size_t off = ((size_t)b*DD + l15 + 16*nt)*EE + 8*lg;
    bwh[nt] = *reinterpret_cast<const short8*>(ho_hi + off);
    bwl[nt] = *reinterpret_cast<const short8*>(ho_lo + off);
  }

  float b1c[4], b2c[4], g1c[4], B1c[4], g2c[4], B2c[4];
  #pragma unroll
  for (int nt = 0; nt < 4; ++nt){
    b1c[nt] = b1[l15 + 16*nt];
    b2c[nt] = b2[l15 + 16*nt];
    g1c[nt] = lng[l15 + 16*nt];
    B1c[nt] = lnb[l15 + 16*nt];
    g2c[nt] = hg[l15 + 16*nt];
    B2c[nt] = hb[l15 + 16*nt];
  }

  const int tpb = MM / 16;                      // 768 tiles per batch
  for (int tl = blk*4 + wid; tl < tpb; tl += CPB4*4){
    const size_t r0 = (size_t)b*MM + (size_t)tl*16;  // global row base
    const int t = (tl*16) >> 10;                // local frame index 0..11

    // ---- k1-part A-fragments ----
    const float* pc = x + (r0 + l15)*DD + k0;
    float4 a00 = *reinterpret_cast<const float4*>(pc);
    float4 a01 = *reinterpret_cast<const float4*>(pc + 4);
    float4 a10 = *reinterpret_cast<const float4*>(pc + 32);
    float4 a11 = *reinterpret_cast<const float4*>(pc + 36);
    if (t > 0){
      const float* pp = pc - (size_t)NN*DD;
      const float4 q00 = *reinterpret_cast<const float4*>(pp);
      const float4 q01 = *reinterpret_cast<const float4*>(pp + 4);
      const float4 q10 = *reinterpret_cast<const float4*>(pp + 32);
      const float4 q11 = *reinterpret_cast<const float4*>(pp + 36);
      a00.x = 0.5f*(a00.x+q00.x); a00.y = 0.5f*(a00.y+q00.y);
      a00.z = 0.5f*(a00.z+q00.z); a00.w = 0.5f*(a00.w+q00.w);
      a01.x = 0.5f*(a01.x+q01.x); a01.y = 0.5f*(a01.y+q01.y);
      a01.z = 0.5f*(a01.z+q01.z); a01.w = 0.5f*(a01.w+q01.w);
      a10.x = 0.5f*(a10.x+q10.x); a10.y = 0.5f*(a10.y+q10.y);
      a10.z = 0.5f*(a10.z+q10.z); a10.w = 0.5f*(a10.w+q10.w);
      a11.x = 0.5f*(a11.x+q11.x); a11.y = 0.5f*(a11.y+q11.y);
      a11.z = 0.5f*(a11.z+q11.z); a11.w = 0.5f*(a11.w+q11.w);
    } else {
      a00.x*=0.5f;a00.y*=0.5f;a00.z*=0.5f;a00.w*=0.5f;
      a01.x*=0.5f;a01.y*=0.5f;a01.z*=0.5f;a01.w*=0.5f;
      a10.x*=0.5f;a10.y*=0.5f;a10.z*=0.5f;a10.w*=0.5f;
      a11.x*=0.5f;a11.y*=0.5f;a11.z*=0.5f;a11.w*=0.5f;
    }
    // shared epilogue x loads (C-layout rows)
    float epi[4][4];
    #pragma unroll
    for (int q = 0; q < 4; ++q){
      const float* pr = x + (r0 + 4*lg + q)*DD + l15;
      #pragma unroll
      for (int nt = 0; nt < 4; ++nt) epi[q][nt] = pr[16*nt];
    }
    // k4-part A-fragments
    const short8 afh = *reinterpret_cast<const short8*>(assign_hi + (r0 + l15)*EE + 8*lg);
    const short8 afl = *reinterpret_cast<const short8*>(assign_lo + (r0 + l15)*EE + 8*lg);

    short8 af[2];
    {
      int4v w;
      w.x = cvt2(a00.x, a00.y); w.y = cvt2(a00.z, a00.w);
      w.z = cvt2(a01.x, a01.y); w.w = cvt2(a01.z, a01.w);
      af[0] = __builtin_bit_cast(short8, w);
      w.x = cvt2(a10.x, a10.y); w.y = cvt2(a10.z, a10.w);
      w.z = cvt2(a11.x, a11.y); w.w = cvt2(a11.z, a11.w);
      af[1] = __builtin_bit_cast(short8, w);
    }

    f32x4 acc1[2][4], acc4[4];
    #pragma unroll
    for (int m = 0; m < 2; ++m)
      #pragma unroll
      for (int nt = 0; nt < 4; ++nt) acc1[m][nt] = (f32x4){0.f,0.f,0.f,0.f};
    #pragma unroll
    for (int nt = 0; nt < 4; ++nt) acc4[nt] = (f32x4){0.f,0.f,0.f,0.f};

    #pragma unroll
    for (int kc = 0; kc < 2; ++kc){
      #pragma unroll
      for (int nt = 0; nt < 4; ++nt){
        acc1[0][nt] = __builtin_amdgcn_mfma_f32_16x16x32_bf16(af[kc], bw[0][nt][kc], acc1[0][nt], 0, 0, 0);
        acc1[1][nt] = __builtin_amdgcn_mfma_f32_16x16x32_bf16(af[kc], bw[1][nt][kc], acc1[1][nt], 0, 0, 0);
      }
    }
    #pragma unroll
    for (int nt = 0; nt < 4; ++nt){
      acc4[nt] = __builtin_amdgcn_mfma_f32_16x16x32_bf16(afh, bwh[nt], acc4[nt], 0, 0, 0);
      acc4[nt] = __builtin_amdgcn_mfma_f32_16x16x32_bf16(afh, bwl[nt], acc4[nt], 0, 0, 0);
      acc4[nt] = __builtin_amdgcn_mfma_f32_16x16x32_bf16(afl, bwh[nt], acc4[nt], 0, 0, 0);
    }

    // ---- dual epilogue: LN1 (stgcn) and LN2 (hyper), interleaved shfl chains ----
    #pragma unroll
    for (int q = 0; q < 4; ++q){
      const size_t row = r0 + 4*lg + q;
      float s1[4], s2[4];
      float rs1 = 0.f, rs2 = 0.f;
      #pragma unroll
      for (int nt = 0; nt < 4; ++nt){
        const float g1 = acc1[0][nt][q] + b1c[nt];
        const float g2 = acc1[1][nt][q] + b2c[nt];
        s1[nt] = fmaxf(g1*g2, 0.f) + g1 + epi[q][nt];
        rs1 += s1[nt];
        s2[nt] = fmaxf(acc4[nt][q], 0.f) + epi[q][nt];
        rs2 += s2[nt];
      }
      #pragma unroll
      for (int off = 8; off; off >>= 1){ rs1 += __shfl_xor(rs1, off); rs2 += __shfl_xor(rs2, off); }
      const float m1 = rs1 * (1.f/DD);
      const float m2 = rs2 * (1.f/DD);
      float d1[4], d2[4]; float v1 = 0.f, v2 = 0.f;
      #pragma unroll
      for (int nt = 0; nt < 4; ++nt){
        d1[nt] = s1[nt] - m1; v1 = fmaf(d1[nt], d1[nt], v1);
        d2[nt] = s2[nt] - m2; v2 = fmaf(d2[nt], d2[nt], v2);
      }
      #pragma unroll
      for (int off = 8; off; off >>= 1){ v1 += __shfl_xor(v1, off); v2 += __shfl_xor(v2, off); }
      const float i1 = rsqrtf(v1 * (1.f/DD) + LN_EPS);
      const float i2 = rsqrtf(v2 * (1.f/DD) + LN_EPS);
      #pragma unroll
      for (int nt = 0; nt < 4; ++nt){
        const float o1 = d1[nt]*i1*g1c[nt] + B1c[nt];
        const float o2 = d2[nt]*i2*g2c[nt] + B2c[nt];
        xout[row*DD + l15 + 16*nt] = 0.5f*(o1 + o2);
      }
    }
  }
}

extern "C" void kernel_launch(void* const* d_in, const int* in_sizes, int n_in,
                              void* d_out, int out_size, void* d_ws, size_t ws_size,
                              hipStream_t stream)
{
  (void)in_sizes; (void)n_in; (void)out_size; (void)ws_size;
  const float* x0  = (const float*)d_in[0];
  const float* W1  = (const float*)d_in[1];
  const float* b1  = (const float*)d_in[2];
  const float* W2  = (const float*)d_in[3];
  const float* b2  = (const float*)d_in[4];
  const float* lng = (const float*)d_in[5];
  const float* lnb = (const float*)d_in[6];
  const float* clf = (const float*)d_in[7];
  const float* em  = (const float*)d_in[8];
  const float* hg  = (const float*)d_in[9];
  const float* hb  = (const float*)d_in[10];
  float* out = (float*)d_out;

  // workspace: x ping f32 | hf_part f32 [BB][CPB2N][EE*DD] | assign hi/lo bf16 | ho hi/lo bf16
  float* ws_x = (float*)d_ws;
  float* hf_part = ws_x + (size_t)ROWS*DD;
  unsigned short* assign_hi = (unsigned short*)(hf_part + (size_t)BB*CPB2N*EE*DD);
  unsigned short* assign_lo = assign_hi + (size_t)ROWS*EE;
  unsigned short* ho_hi     = assign_lo + (size_t)ROWS*EE;
  unsigned short* ho_lo     = ho_hi + (size_t)BB*DD*EE;

  // ping-pong so xin != xout at EVERY depth (k14 reads t-1 rows cross-tile):
  // depth 0: x0 -> d_out ; depth 1: d_out -> ws_x ; depth 2: ws_x -> d_out (final)
  const float* xin_seq[3]  = { x0, out, ws_x };
  float*       xout_seq[3] = { out, ws_x, out };

  for (int i = 0; i < 3; ++i){
    const float* xin = xin_seq[i];
    float* xout = xout_seq[i];
    k2_hyper1<<<BB*CPB2N, 256, 0, stream>>>(xin, clf, assign_hi, assign_lo, hf_part);
    k3_edge<<<BB, 256, 0, stream>>>(hf_part, em, ho_hi, ho_lo);
    k14_fused<<<BB*CPB4, 256, 0, stream>>>(xin, W1 + i*DD*DD, b1 + i*DD,
                                           W2 + i*DD*DD, b2 + i*DD,
                                           lng + i*DD, lnb + i*DD,
                                           assign_hi, assign_lo, ho_hi, ho_lo,
                                           hg, hb, xout);
  }
}

// Round 13
// 316.835 us; speedup vs baseline: 1.2970x; 1.0265x over previous
//
#include <hip/hip_runtime.h>

#define BB 16
#define TT 12
#define NN 1024
#define DD 64
#define EE 32
#define MM (TT*NN)          // 12288 rows per batch
#define ROWS (BB*MM)        // 196608 total rows
#define CPB2N 48            // k2 blocks per batch
#define CPB4 64             // k14 blocks per batch -> grid 1024 = 4 blocks/CU (VGPR=104 allows 4 waves/SIMD)
#define LN_EPS 1e-5f

typedef __attribute__((ext_vector_type(8))) short short8;
typedef __attribute__((ext_vector_type(4))) float f32x4;
typedef __attribute__((ext_vector_type(4))) int   int4v;

// pack two f32 -> one dword of 2 bf16 (RNE), low = a, high = b
__device__ __forceinline__ int cvt2(float a, float b){
  int r;
  asm("v_cvt_pk_bf16_f32 %0, %1, %2" : "=v"(r) : "v"(a), "v"(b));
  return r;
}
__device__ __forceinline__ unsigned short bf16of(float a){
  return (unsigned short)(cvt2(a, a) & 0xffff);
}
__device__ __forceinline__ float f32of(unsigned short h){
  return __builtin_bit_cast(float, (unsigned int)h << 16);
}
__device__ __forceinline__ float lo16f(int w){ return __builtin_bit_cast(float, (unsigned int)w << 16); }
__device__ __forceinline__ float hi16f(int w){ return __builtin_bit_cast(float, (unsigned int)w & 0xffff0000u); }

__device__ __forceinline__ short8 pack_hi8(const float* v){
  int4v w;
  w.x = cvt2(v[0], v[1]); w.y = cvt2(v[2], v[3]);
  w.z = cvt2(v[4], v[5]); w.w = cvt2(v[6], v[7]);
  return __builtin_bit_cast(short8, w);
}
__device__ __forceinline__ short8 pack_lo8(const float* v, short8 hi){
  const int4v wh = __builtin_bit_cast(int4v, hi);
  float r[8];
  r[0] = v[0] - lo16f(wh.x); r[1] = v[1] - hi16f(wh.x);
  r[2] = v[2] - lo16f(wh.y); r[3] = v[3] - hi16f(wh.y);
  r[4] = v[4] - lo16f(wh.z); r[5] = v[5] - hi16f(wh.z);
  r[6] = v[6] - lo16f(wh.w); r[7] = v[7] - hi16f(wh.w);
  return pack_hi8(r);
}

// ---------------- K2: full-MFMA hyper stage 1 (verbatim round 7/12, PASSING) ----------------
__global__ __launch_bounds__(256, 3)
void k2_hyper1(const float* __restrict__ x, const float* __restrict__ clf,
               unsigned short* __restrict__ assign_hi, unsigned short* __restrict__ assign_lo,
               float* __restrict__ hf_part)
{
  __shared__ __align__(16) float lbuf[4224];   // union: amat 4x[32][33] | red 2x[32][65]
  const int lane = threadIdx.x & 63;
  const int wid  = threadIdx.x >> 6;
  const int l15  = lane & 15;
  const int lg   = lane >> 4;
  const int b    = blockIdx.x / CPB2N;
  const int blk  = blockIdx.x % CPB2N;
  float* amat = lbuf + wid*1056;               // [32][33] f32 per wave

  short8 bch[2][2], bcl[2][2];
  #pragma unroll
  for (int kc = 0; kc < 2; ++kc)
    #pragma unroll
    for (int nt = 0; nt < 2; ++nt){
      float v[8];
      #pragma unroll
      for (int j = 0; j < 8; ++j)
        v[j] = clf[(size_t)(32*kc + 8*lg + j)*EE + 16*nt + l15];
      bch[kc][nt] = pack_hi8(v);
      bcl[kc][nt] = pack_lo8(v, bch[kc][nt]);
    }

  f32x4 acc2[2][4];
  #pragma unroll
  for (int et = 0; et < 2; ++et)
    #pragma unroll
    for (int dt = 0; dt < 4; ++dt) acc2[et][dt] = (f32x4){0.f,0.f,0.f,0.f};

  const int wslot = blk*4 + wid;               // 0..191
  #pragma unroll 1
  for (int s = 0; s < 2; ++s){
    const int c = wslot + s*192;
    const size_t grb = (size_t)b*MM + (size_t)c*32;

    #pragma unroll 1
    for (int h = 0; h < 2; ++h){
      short8 axh[2], axl[2];
      #pragma unroll
      for (int kc = 0; kc < 2; ++kc){
        const float* p = x + (grb + 16*h + l15)*DD + 32*kc + 8*lg;
        float v[8];
        const float4 p0 = *reinterpret_cast<const float4*>(p);
        const float4 p1 = *reinterpret_cast<const float4*>(p + 4);
        v[0]=p0.x; v[1]=p0.y; v[2]=p0.z; v[3]=p0.w;
        v[4]=p1.x; v[5]=p1.y; v[6]=p1.z; v[7]=p1.w;
        axh[kc] = pack_hi8(v); axl[kc] = pack_lo8(v, axh[kc]);
      }
      f32x4 accL[2] = {(f32x4){0.f,0.f,0.f,0.f},(f32x4){0.f,0.f,0.f,0.f}};
      #pragma unroll
      for (int kc = 0; kc < 2; ++kc)
        #pragma unroll
        for (int nt = 0; nt < 2; ++nt){
          accL[nt] = __builtin_amdgcn_mfma_f32_16x16x32_bf16(axh[kc], bch[kc][nt], accL[nt], 0, 0, 0);
          accL[nt] = __builtin_amdgcn_mfma_f32_16x16x32_bf16(axh[kc], bcl[kc][nt], accL[nt], 0, 0, 0);
          accL[nt] = __builtin_amdgcn_mfma_f32_16x16x32_bf16(axl[kc], bch[kc][nt], accL[nt], 0, 0, 0);
        }
      #pragma unroll
      for (int q = 0; q < 4; ++q){
        const float l0 = accL[0][q], l1 = accL[1][q];
        float mx = fmaxf(l0, l1);
        #pragma unroll
        for (int off = 8; off; off >>= 1) mx = fmaxf(mx, __shfl_xor(mx, off));
        const float e0 = expf(l0 - mx), e1 = expf(l1 - mx);
        float sm = e0 + e1;
        #pragma unroll
        for (int off = 8; off; off >>= 1) sm += __shfl_xor(sm, off);
        const float inv = 1.f / sm;
        const float a0 = e0*inv, a1 = e1*inv;
        const int rloc = 16*h + 4*lg + q;
        const size_t row = grb + rloc;
        const unsigned short h0 = bf16of(a0);
        const unsigned short h1 = bf16of(a1);
        assign_hi[row*EE + l15]      = h0;
        assign_hi[row*EE + 16 + l15] = h1;
        assign_lo[row*EE + l15]      = bf16of(a0 - f32of(h0));
        assign_lo[row*EE + 16 + l15] = bf16of(a1 - f32of(h1));
        amat[rloc*33 + l15]      = a0;
        amat[rloc*33 + 16 + l15] = a1;
      }
    }
    __builtin_amdgcn_wave_barrier();
    short8 a2h[2], a2l[2];
    #pragma unroll
    for (int et = 0; et < 2; ++et){
      float v[8];
      #pragma unroll
      for (int j = 0; j < 8; ++j)
        v[j] = amat[(8*lg + j)*33 + 16*et + l15];
      a2h[et] = pack_hi8(v); a2l[et] = pack_lo8(v, a2h[et]);
    }
    #pragma unroll
    for (int dt = 0; dt < 4; ++dt){
      float v[8];
      #pragma unroll
      for (int j = 0; j < 8; ++j)
        v[j] = x[(grb + 8*lg + j)*DD + 16*dt + l15];
      const short8 b2 = pack_hi8(v);
      #pragma unroll
      for (int et = 0; et < 2; ++et){
        acc2[et][dt] = __builtin_amdgcn_mfma_f32_16x16x32_bf16(a2h[et], b2, acc2[et][dt], 0, 0, 0);
        acc2[et][dt] = __builtin_amdgcn_mfma_f32_16x16x32_bf16(a2l[et], b2, acc2[et][dt], 0, 0, 0);
      }
    }
    __builtin_amdgcn_wave_barrier();
  }

  __syncthreads();
  float* red = lbuf;
  if (wid < 2){
    #pragma unroll
    for (int et = 0; et < 2; ++et)
      #pragma unroll
      for (int dt = 0; dt < 4; ++dt)
        #pragma unroll
        for (int q = 0; q < 4; ++q)
          red[wid*2080 + (16*et + 4*lg + q)*65 + 16*dt + l15] = acc2[et][dt][q];
  }
  __syncthreads();
  if (wid >= 2){
    #pragma unroll
    for (int et = 0; et < 2; ++et)
      #pragma unroll
      for (int dt = 0; dt < 4; ++dt)
        #pragma unroll
        for (int q = 0; q < 4; ++q)
          red[(wid-2)*2080 + (16*et + 4*lg + q)*65 + 16*dt + l15] += acc2[et][dt][q];
  }
  __syncthreads();
  float* dst = hf_part + ((size_t)b*CPB2N + blk)*(EE*DD);
  for (int i = threadIdx.x; i < EE*DD; i += 256){
    const int e = i >> 6, d = i & 63;
    dst[i] = red[e*65 + d] + red[2080 + e*65 + d];
  }
}

// ---------------- K3: sum hf_part slots; ho = relu(em @ hf) + hf; emit transposed bf16 hi/lo ----------------
__global__ void k3_edge(const float* __restrict__ hf_part, const float* __restrict__ em,
                        unsigned short* __restrict__ ho_hi, unsigned short* __restrict__ ho_lo)
{
  __shared__ float ems[EE*EE];
  __shared__ float hfs[EE*DD];
  const int b = blockIdx.x;
  const int tid = threadIdx.x;
  for (int i = tid; i < EE*EE; i += 256) ems[i] = em[i];
  for (int i = tid; i < EE*DD; i += 256){
    const float* p = hf_part + (size_t)b*CPB2N*(EE*DD) + i;
    float s0=0.f, s1=0.f, s2=0.f, s3=0.f;
    #pragma unroll
    for (int k = 0; k < CPB2N; k += 4){
      s0 += p[(size_t)(k+0)*EE*DD]; s1 += p[(size_t)(k+1)*EE*DD];
      s2 += p[(size_t)(k+2)*EE*DD]; s3 += p[(size_t)(k+3)*EE*DD];
    }
    hfs[i] = (s0+s1)+(s2+s3);
  }
  __syncthreads();
  for (int i = tid; i < EE*DD; i += 256){
    const int e = i >> 6, d = i & 63;
    float acc = 0.f;
    #pragma unroll
    for (int f = 0; f < EE; ++f) acc = fmaf(ems[e*EE+f], hfs[f*DD+d], acc);
    const float v = fmaxf(acc, 0.f) + hfs[e*DD+d];
    const unsigned short hi = bf16of(v);
    const unsigned short lo = bf16of(v - f32of(hi));
    ho_hi[((size_t)b*DD + d)*EE + e] = hi;
    ho_lo[((size_t)b*DD + d)*EE + e] = lo;
  }
}

// ---------------- K14: fused STGCN + hyper-combine per tile (no out1 buffer) ----------------
// REQUIRES xin != xout (launcher ping-pongs): reads x[t-1] rows cross-tile.
__global__ __launch_bounds__(256, 2)
void k14_fused(const float* __restrict__ x,
               const float* __restrict__ W1, const float* __restrict__ b1,
               const float* __restrict__ W2, const float* __restrict__ b2,
               const float* __restrict__ lng, const float* __restrict__ lnb,
               const unsigned short* __restrict__ assign_hi,
               const unsigned short* __restrict__ assign_lo,
               const unsigned short* __restrict__ ho_hi,
               const unsigned short* __restrict__ ho_lo,
               const float* __restrict__ hg, const float* __restrict__ hb,
               float* __restrict__ xout)
{
  const int lane = threadIdx.x & 63;
  const int wid  = threadIdx.x >> 6;
  const int b    = blockIdx.x / CPB4;
  const int blk  = blockIdx.x % CPB4;
  const int l15  = lane & 15;
  const int lg   = lane >> 4;
  const int k0   = lg * 8;

  // W fragments (k1 part)
  short8 bw[2][4][2];
  const float* Wm[2] = {W1, W2};
  #pragma unroll
  for (int m = 0; m < 2; ++m)
    #pragma unroll
    for (int nt = 0; nt < 4; ++nt)
      #pragma unroll
      for (int kc = 0; kc < 2; ++kc){
        const float* src = Wm[m] + (size_t)(16*nt + l15)*DD + 32*kc + k0;
        const float4 p0 = *reinterpret_cast<const float4*>(src);
        const float4 p1 = *reinterpret_cast<const float4*>(src + 4);
        int4v w;
        w.x = cvt2(p0.x, p0.y); w.y = cvt2(p0.z, p0.w);
        w.z = cvt2(p1.x, p1.y); w.w = cvt2(p1.z, p1.w);
        bw[m][nt][kc] = __builtin_bit_cast(short8, w);
      }

  // ho fragments (k4 part, per batch)
  short8 bwh[4], bwl[4];
  #pragma unroll
  for (int nt = 0; nt < 4; ++nt){
    const size_t off = ((size_t)b*DD + l15 + 16*nt)*EE + 8*lg;
    bwh[nt] = *reinterpret_cast<const short8*>(ho_hi + off);
    bwl[nt] = *reinterpret_cast<const short8*>(ho_lo + off);
  }

  float b1c[4], b2c[4], g1c[4], B1c[4], g2c[4], B2c[4];
  #pragma unroll
  for (int nt = 0; nt < 4; ++nt){
    b1c[nt] = b1[l15 + 16*nt];
    b2c[nt] = b2[l15 + 16*nt];
    g1c[nt] = lng[l15 + 16*nt];
    B1c[nt] = lnb[l15 + 16*nt];
    g2c[nt] = hg[l15 + 16*nt];
    B2c[nt] = hb[l15 + 16*nt];
  }

  const int tpb = MM / 16;                      // 768 tiles per batch; 3 tiles/wave at CPB4=64
  for (int tl = blk*4 + wid; tl < tpb; tl += CPB4*4){
    const size_t r0 = (size_t)b*MM + (size_t)tl*16;  // global row base
    const int t = (tl*16) >> 10;                // local frame index 0..11

    // ---- k1-part A-fragments ----
    const float* pc = x + (r0 + l15)*DD + k0;
    float4 a00 = *reinterpret_cast<const float4*>(pc);
    float4 a01 = *reinterpret_cast<const float4*>(pc + 4);
    float4 a10 = *reinterpret_cast<const float4*>(pc + 32);
    float4 a11 = *reinterpret_cast<const float4*>(pc + 36);
    if (t > 0){
      const float* pp = pc - (size_t)NN*DD;
      const float4 q00 = *reinterpret_cast<const float4*>(pp);
      const float4 q01 = *reinterpret_cast<const float4*>(pp + 4);
      const float4 q10 = *reinterpret_cast<const float4*>(pp + 32);
      const float4 q11 = *reinterpret_cast<const float4*>(pp + 36);
      a00.x = 0.5f*(a00.x+q00.x); a00.y = 0.5f*(a00.y+q00.y);
      a00.z = 0.5f*(a00.z+q00.z); a00.w = 0.5f*(a00.w+q00.w);
      a01.x = 0.5f*(a01.x+q01.x); a01.y = 0.5f*(a01.y+q01.y);
      a01.z = 0.5f*(a01.z+q01.z); a01.w = 0.5f*(a01.w+q01.w);
      a10.x = 0.5f*(a10.x+q10.x); a10.y = 0.5f*(a10.y+q10.y);
      a10.z = 0.5f*(a10.z+q10.z); a10.w = 0.5f*(a10.w+q10.w);
      a11.x = 0.5f*(a11.x+q11.x); a11.y = 0.5f*(a11.y+q11.y);
      a11.z = 0.5f*(a11.z+q11.z); a11.w = 0.5f*(a11.w+q11.w);
    } else {
      a00.x*=0.5f;a00.y*=0.5f;a00.z*=0.5f;a00.w*=0.5f;
      a01.x*=0.5f;a01.y*=0.5f;a01.z*=0.5f;a01.w*=0.5f;
      a10.x*=0.5f;a10.y*=0.5f;a10.z*=0.5f;a10.w*=0.5f;
      a11.x*=0.5f;a11.y*=0.5f;a11.z*=0.5f;a11.w*=0.5f;
    }
    // shared epilogue x loads (C-layout rows)
    float epi[4][4];
    #pragma unroll
    for (int q = 0; q < 4; ++q){
      const float* pr = x + (r0 + 4*lg + q)*DD + l15;
      #pragma unroll
      for (int nt = 0; nt < 4; ++nt) epi[q][nt] = pr[16*nt];
    }
    // k4-part A-fragments
    const short8 afh = *reinterpret_cast<const short8*>(assign_hi + (r0 + l15)*EE + 8*lg);
    const short8 afl = *reinterpret_cast<const short8*>(assign_lo + (r0 + l15)*EE + 8*lg);

    short8 af[2];
    {
      int4v w;
      w.x = cvt2(a00.x, a00.y); w.y = cvt2(a00.z, a00.w);
      w.z = cvt2(a01.x, a01.y); w.w = cvt2(a01.z, a01.w);
      af[0] = __builtin_bit_cast(short8, w);
      w.x = cvt2(a10.x, a10.y); w.y = cvt2(a10.z, a10.w);
      w.z = cvt2(a11.x, a11.y); w.w = cvt2(a11.z, a11.w);
      af[1] = __builtin_bit_cast(short8, w);
    }

    f32x4 acc1[2][4], acc4[4];
    #pragma unroll
    for (int m = 0; m < 2; ++m)
      #pragma unroll
      for (int nt = 0; nt < 4; ++nt) acc1[m][nt] = (f32x4){0.f,0.f,0.f,0.f};
    #pragma unroll
    for (int nt = 0; nt < 4; ++nt) acc4[nt] = (f32x4){0.f,0.f,0.f,0.f};

    #pragma unroll
    for (int kc = 0; kc < 2; ++kc){
      #pragma unroll
      for (int nt = 0; nt < 4; ++nt){
        acc1[0][nt] = __builtin_amdgcn_mfma_f32_16x16x32_bf16(af[kc], bw[0][nt][kc], acc1[0][nt], 0, 0, 0);
        acc1[1][nt] = __builtin_amdgcn_mfma_f32_16x16x32_bf16(af[kc], bw[1][nt][kc], acc1[1][nt], 0, 0, 0);
      }
    }
    #pragma unroll
    for (int nt = 0; nt < 4; ++nt){
      acc4[nt] = __builtin_amdgcn_mfma_f32_16x16x32_bf16(afh, bwh[nt], acc4[nt], 0, 0, 0);
      acc4[nt] = __builtin_amdgcn_mfma_f32_16x16x32_bf16(afh, bwl[nt], acc4[nt], 0, 0, 0);
      acc4[nt] = __builtin_amdgcn_mfma_f32_16x16x32_bf16(afl, bwh[nt], acc4[nt], 0, 0, 0);
    }

    // ---- dual epilogue: LN1 (stgcn) and LN2 (hyper), interleaved shfl chains ----
    #pragma unroll
    for (int q = 0; q < 4; ++q){
      const size_t row = r0 + 4*lg + q;
      float s1[4], s2[4];
      float rs1 = 0.f, rs2 = 0.f;
      #pragma unroll
      for (int nt = 0; nt < 4; ++nt){
        const float g1 = acc1[0][nt][q] + b1c[nt];
        const float g2 = acc1[1][nt][q] + b2c[nt];
        s1[nt] = fmaxf(g1*g2, 0.f) + g1 + epi[q][nt];
        rs1 += s1[nt];
        s2[nt] = fmaxf(acc4[nt][q], 0.f) + epi[q][nt];
        rs2 += s2[nt];
      }
      #pragma unroll
      for (int off = 8; off; off >>= 1){ rs1 += __shfl_xor(rs1, off); rs2 += __shfl_xor(rs2, off); }
      const float m1 = rs1 * (1.f/DD);
      const float m2 = rs2 * (1.f/DD);
      float d1[4], d2[4]; float v1 = 0.f, v2 = 0.f;
      #pragma unroll
      for (int nt = 0; nt < 4; ++nt){
        d1[nt] = s1[nt] - m1; v1 = fmaf(d1[nt], d1[nt], v1);
        d2[nt] = s2[nt] - m2; v2 = fmaf(d2[nt], d2[nt], v2);
      }
      #pragma unroll
      for (int off = 8; off; off >>= 1){ v1 += __shfl_xor(v1, off); v2 += __shfl_xor(v2, off); }
      const float i1 = rsqrtf(v1 * (1.f/DD) + LN_EPS);
      const float i2 = rsqrtf(v2 * (1.f/DD) + LN_EPS);
      #pragma unroll
      for (int nt = 0; nt < 4; ++nt){
        const float o1 = d1[nt]*i1*g1c[nt] + B1c[nt];
        const float o2 = d2[nt]*i2*g2c[nt] + B2c[nt];
        xout[row*DD + l15 + 16*nt] = 0.5f*(o1 + o2);
      }
    }
  }
}

extern "C" void kernel_launch(void* const* d_in, const int* in_sizes, int n_in,
                              void* d_out, int out_size, void* d_ws, size_t ws_size,
                              hipStream_t stream)
{
  (void)in_sizes; (void)n_in; (void)out_size; (void)ws_size;
  const float* x0  = (const float*)d_in[0];
  const float* W1  = (const float*)d_in[1];
  const float* b1  = (const float*)d_in[2];
  const float* W2  = (const float*)d_in[3];
  const float* b2  = (const float*)d_in[4];
  const float* lng = (const float*)d_in[5];
  const float* lnb = (const float*)d_in[6];
  const float* clf = (const float*)d_in[7];
  const float* em  = (const float*)d_in[8];
  const float* hg  = (const float*)d_in[9];
  const float* hb  = (const float*)d_in[10];
  float* out = (float*)d_out;

  // workspace: x ping f32 | hf_part f32 [BB][CPB2N][EE*DD] | assign hi/lo bf16 | ho hi/lo bf16
  float* ws_x = (float*)d_ws;
  float* hf_part = ws_x + (size_t)ROWS*DD;
  unsigned short* assign_hi = (unsigned short*)(hf_part + (size_t)BB*CPB2N*EE*DD);
  unsigned short* assign_lo = assign_hi + (size_t)ROWS*EE;
  unsigned short* ho_hi     = assign_lo + (size_t)ROWS*EE;
  unsigned short* ho_lo     = ho_hi + (size_t)BB*DD*EE;

  // ping-pong so xin != xout at EVERY depth (k14 reads t-1 rows cross-tile):
  // depth 0: x0 -> d_out ; depth 1: d_out -> ws_x ; depth 2: ws_x -> d_out (final)
  const float* xin_seq[3]  = { x0, out, ws_x };
  float*       xout_seq[3] = { out, ws_x, out };

  for (int i = 0; i < 3; ++i){
    const float* xin = xin_seq[i];
    float* xout = xout_seq[i];
    k2_hyper1<<<BB*CPB2N, 256, 0, stream>>>(xin, clf, assign_hi, assign_lo, hf_part);
    k3_edge<<<BB, 256, 0, stream>>>(hf_part, em, ho_hi, ho_lo);
    k14_fused<<<BB*CPB4, 256, 0, stream>>>(xin, W1 + i*DD*DD, b1 + i*DD,
                                           W2 + i*DD*DD, b2 + i*DD,
                                           lng + i*DD, lnb + i*DD,
                                           assign_hi, assign_lo, ho_hi, ho_lo,
                                           hg, hb, xout);
  }
}

// Round 14
// 287.285 us; speedup vs baseline: 1.4304x; 1.1029x over previous
//
#include <hip/hip_runtime.h>

#define BB 16
#define TT 12
#define NN 1024
#define DD 64
#define EE 32
#define MM (TT*NN)          // 12288 rows per batch
#define ROWS (BB*MM)        // 196608 total rows
#define CPB2N 96            // k2 blocks per batch -> grid 1536; 1 chunk/wave
#define S_ITER (384/(CPB2N*4))   // chunks per wave (384 chunks of 32 rows per batch)
#define CPB4 96             // k14 blocks per batch -> grid 1536 = 6 blocks/CU, 2 tiles/wave
#define LN_EPS 1e-5f

typedef __attribute__((ext_vector_type(8))) short short8;
typedef __attribute__((ext_vector_type(4))) float f32x4;
typedef __attribute__((ext_vector_type(4))) int   int4v;

// pack two f32 -> one dword of 2 bf16 (RNE), low = a, high = b
__device__ __forceinline__ int cvt2(float a, float b){
  int r;
  asm("v_cvt_pk_bf16_f32 %0, %1, %2" : "=v"(r) : "v"(a), "v"(b));
  return r;
}
__device__ __forceinline__ unsigned short bf16of(float a){
  return (unsigned short)(cvt2(a, a) & 0xffff);
}
__device__ __forceinline__ float f32of(unsigned short h){
  return __builtin_bit_cast(float, (unsigned int)h << 16);
}
__device__ __forceinline__ float lo16f(int w){ return __builtin_bit_cast(float, (unsigned int)w << 16); }
__device__ __forceinline__ float hi16f(int w){ return __builtin_bit_cast(float, (unsigned int)w & 0xffff0000u); }

__device__ __forceinline__ short8 pack_hi8(const float* v){
  int4v w;
  w.x = cvt2(v[0], v[1]); w.y = cvt2(v[2], v[3]);
  w.z = cvt2(v[4], v[5]); w.w = cvt2(v[6], v[7]);
  return __builtin_bit_cast(short8, w);
}
__device__ __forceinline__ short8 pack_lo8(const float* v, short8 hi){
  const int4v wh = __builtin_bit_cast(int4v, hi);
  float r[8];
  r[0] = v[0] - lo16f(wh.x); r[1] = v[1] - hi16f(wh.x);
  r[2] = v[2] - lo16f(wh.y); r[3] = v[3] - hi16f(wh.y);
  r[4] = v[4] - lo16f(wh.z); r[5] = v[5] - hi16f(wh.z);
  r[6] = v[6] - lo16f(wh.w); r[7] = v[7] - hi16f(wh.w);
  return pack_hi8(r);
}

// ---------------- K2: full-MFMA hyper stage 1 (round-7 body; chunk mapping generic in CPB2N) ----------------
__global__ __launch_bounds__(256, 3)
void k2_hyper1(const float* __restrict__ x, const float* __restrict__ clf,
               unsigned short* __restrict__ assign_hi, unsigned short* __restrict__ assign_lo,
               float* __restrict__ hf_part)
{
  __shared__ __align__(16) float lbuf[4224];   // union: amat 4x[32][33] | red 2x[32][65]
  const int lane = threadIdx.x & 63;
  const int wid  = threadIdx.x >> 6;
  const int l15  = lane & 15;
  const int lg   = lane >> 4;
  const int b    = blockIdx.x / CPB2N;
  const int blk  = blockIdx.x % CPB2N;
  float* amat = lbuf + wid*1056;               // [32][33] f32 per wave

  short8 bch[2][2], bcl[2][2];
  #pragma unroll
  for (int kc = 0; kc < 2; ++kc)
    #pragma unroll
    for (int nt = 0; nt < 2; ++nt){
      float v[8];
      #pragma unroll
      for (int j = 0; j < 8; ++j)
        v[j] = clf[(size_t)(32*kc + 8*lg + j)*EE + 16*nt + l15];
      bch[kc][nt] = pack_hi8(v);
      bcl[kc][nt] = pack_lo8(v, bch[kc][nt]);
    }

  f32x4 acc2[2][4];
  #pragma unroll
  for (int et = 0; et < 2; ++et)
    #pragma unroll
    for (int dt = 0; dt < 4; ++dt) acc2[et][dt] = (f32x4){0.f,0.f,0.f,0.f};

  const int wslot = blk*4 + wid;               // 0..CPB2N*4-1
  #pragma unroll 1
  for (int s = 0; s < S_ITER; ++s){
    const int c = wslot + s*(CPB2N*4);         // chunk id, covers 0..383 exactly once
    const size_t grb = (size_t)b*MM + (size_t)c*32;

    #pragma unroll 1
    for (int h = 0; h < 2; ++h){
      short8 axh[2], axl[2];
      #pragma unroll
      for (int kc = 0; kc < 2; ++kc){
        const float* p = x + (grb + 16*h + l15)*DD + 32*kc + 8*lg;
        float v[8];
        const float4 p0 = *reinterpret_cast<const float4*>(p);
        const float4 p1 = *reinterpret_cast<const float4*>(p + 4);
        v[0]=p0.x; v[1]=p0.y; v[2]=p0.z; v[3]=p0.w;
        v[4]=p1.x; v[5]=p1.y; v[6]=p1.z; v[7]=p1.w;
        axh[kc] = pack_hi8(v); axl[kc] = pack_lo8(v, axh[kc]);
      }
      f32x4 accL[2] = {(f32x4){0.f,0.f,0.f,0.f},(f32x4){0.f,0.f,0.f,0.f}};
      #pragma unroll
      for (int kc = 0; kc < 2; ++kc)
        #pragma unroll
        for (int nt = 0; nt < 2; ++nt){
          accL[nt] = __builtin_amdgcn_mfma_f32_16x16x32_bf16(axh[kc], bch[kc][nt], accL[nt], 0, 0, 0);
          accL[nt] = __builtin_amdgcn_mfma_f32_16x16x32_bf16(axh[kc], bcl[kc][nt], accL[nt], 0, 0, 0);
          accL[nt] = __builtin_amdgcn_mfma_f32_16x16x32_bf16(axl[kc], bch[kc][nt], accL[nt], 0, 0, 0);
        }
      #pragma unroll
      for (int q = 0; q < 4; ++q){
        const float l0 = accL[0][q], l1 = accL[1][q];
        float mx = fmaxf(l0, l1);
        #pragma unroll
        for (int off = 8; off; off >>= 1) mx = fmaxf(mx, __shfl_xor(mx, off));
        const float e0 = expf(l0 - mx), e1 = expf(l1 - mx);
        float sm = e0 + e1;
        #pragma unroll
        for (int off = 8; off; off >>= 1) sm += __shfl_xor(sm, off);
        const float inv = 1.f / sm;
        const float a0 = e0*inv, a1 = e1*inv;
        const int rloc = 16*h + 4*lg + q;
        const size_t row = grb + rloc;
        const unsigned short h0 = bf16of(a0);
        const unsigned short h1 = bf16of(a1);
        assign_hi[row*EE + l15]      = h0;
        assign_hi[row*EE + 16 + l15] = h1;
        assign_lo[row*EE + l15]      = bf16of(a0 - f32of(h0));
        assign_lo[row*EE + 16 + l15] = bf16of(a1 - f32of(h1));
        amat[rloc*33 + l15]      = a0;
        amat[rloc*33 + 16 + l15] = a1;
      }
    }
    __builtin_amdgcn_wave_barrier();
    short8 a2h[2], a2l[2];
    #pragma unroll
    for (int et = 0; et < 2; ++et){
      float v[8];
      #pragma unroll
      for (int j = 0; j < 8; ++j)
        v[j] = amat[(8*lg + j)*33 + 16*et + l15];
      a2h[et] = pack_hi8(v); a2l[et] = pack_lo8(v, a2h[et]);
    }
    #pragma unroll
    for (int dt = 0; dt < 4; ++dt){
      float v[8];
      #pragma unroll
      for (int j = 0; j < 8; ++j)
        v[j] = x[(grb + 8*lg + j)*DD + 16*dt + l15];
      const short8 b2 = pack_hi8(v);
      #pragma unroll
      for (int et = 0; et < 2; ++et){
        acc2[et][dt] = __builtin_amdgcn_mfma_f32_16x16x32_bf16(a2h[et], b2, acc2[et][dt], 0, 0, 0);
        acc2[et][dt] = __builtin_amdgcn_mfma_f32_16x16x32_bf16(a2l[et], b2, acc2[et][dt], 0, 0, 0);
      }
    }
    __builtin_amdgcn_wave_barrier();
  }

  __syncthreads();
  float* red = lbuf;
  if (wid < 2){
    #pragma unroll
    for (int et = 0; et < 2; ++et)
      #pragma unroll
      for (int dt = 0; dt < 4; ++dt)
        #pragma unroll
        for (int q = 0; q < 4; ++q)
          red[wid*2080 + (16*et + 4*lg + q)*65 + 16*dt + l15] = acc2[et][dt][q];
  }
  __syncthreads();
  if (wid >= 2){
    #pragma unroll
    for (int et = 0; et < 2; ++et)
      #pragma unroll
      for (int dt = 0; dt < 4; ++dt)
        #pragma unroll
        for (int q = 0; q < 4; ++q)
          red[(wid-2)*2080 + (16*et + 4*lg + q)*65 + 16*dt + l15] += acc2[et][dt][q];
  }
  __syncthreads();
  float* dst = hf_part + ((size_t)b*CPB2N + blk)*(EE*DD);
  for (int i = threadIdx.x; i < EE*DD; i += 256){
    const int e = i >> 6, d = i & 63;
    dst[i] = red[e*65 + d] + red[2080 + e*65 + d];
  }
}

// ---------------- K3: sum hf_part slots; ho = relu(em @ hf) + hf; emit transposed bf16 hi/lo ----------------
__global__ void k3_edge(const float* __restrict__ hf_part, const float* __restrict__ em,
                        unsigned short* __restrict__ ho_hi, unsigned short* __restrict__ ho_lo)
{
  __shared__ float ems[EE*EE];
  __shared__ float hfs[EE*DD];
  const int b = blockIdx.x;
  const int tid = threadIdx.x;
  for (int i = tid; i < EE*EE; i += 256) ems[i] = em[i];
  for (int i = tid; i < EE*DD; i += 256){
    const float* p = hf_part + (size_t)b*CPB2N*(EE*DD) + i;
    float s0=0.f, s1=0.f, s2=0.f, s3=0.f;
    #pragma unroll
    for (int k = 0; k < CPB2N; k += 4){
      s0 += p[(size_t)(k+0)*EE*DD]; s1 += p[(size_t)(k+1)*EE*DD];
      s2 += p[(size_t)(k+2)*EE*DD]; s3 += p[(size_t)(k+3)*EE*DD];
    }
    hfs[i] = (s0+s1)+(s2+s3);
  }
  __syncthreads();
  for (int i = tid; i < EE*DD; i += 256){
    const int e = i >> 6, d = i & 63;
    float acc = 0.f;
    #pragma unroll
    for (int f = 0; f < EE; ++f) acc = fmaf(ems[e*EE+f], hfs[f*DD+d], acc);
    const float v = fmaxf(acc, 0.f) + hfs[e*DD+d];
    const unsigned short hi = bf16of(v);
    const unsigned short lo = bf16of(v - f32of(hi));
    ho_hi[((size_t)b*DD + d)*EE + e] = hi;
    ho_lo[((size_t)b*DD + d)*EE + e] = lo;
  }
}

// ---------------- K14: fused STGCN + hyper-combine per tile (no out1 buffer) ----------------
// REQUIRES xin != xout (launcher ping-pongs): reads x[t-1] rows cross-tile.
__global__ __launch_bounds__(256, 2)
void k14_fused(const float* __restrict__ x,
               const float* __restrict__ W1, const float* __restrict__ b1,
               const float* __restrict__ W2, const float* __restrict__ b2,
               const float* __restrict__ lng, const float* __restrict__ lnb,
               const unsigned short* __restrict__ assign_hi,
               const unsigned short* __restrict__ assign_lo,
               const unsigned short* __restrict__ ho_hi,
               const unsigned short* __restrict__ ho_lo,
               const float* __restrict__ hg, const float* __restrict__ hb,
               float* __restrict__ xout)
{
  const int lane = threadIdx.x & 63;
  const int wid  = threadIdx.x >> 6;
  const int b    = blockIdx.x / CPB4;
  const int blk  = blockIdx.x % CPB4;
  const int l15  = lane & 15;
  const int lg   = lane >> 4;
  const int k0   = lg * 8;

  // W fragments (k1 part)
  short8 bw[2][4][2];
  const float* Wm[2] = {W1, W2};
  #pragma unroll
  for (int m = 0; m < 2; ++m)
    #pragma unroll
    for (int nt = 0; nt < 4; ++nt)
      #pragma unroll
      for (int kc = 0; kc < 2; ++kc){
        const float* src = Wm[m] + (size_t)(16*nt + l15)*DD + 32*kc + k0;
        const float4 p0 = *reinterpret_cast<const float4*>(src);
        const float4 p1 = *reinterpret_cast<const float4*>(src + 4);
        int4v w;
        w.x = cvt2(p0.x, p0.y); w.y = cvt2(p0.z, p0.w);
        w.z = cvt2(p1.x, p1.y); w.w = cvt2(p1.z, p1.w);
        bw[m][nt][kc] = __builtin_bit_cast(short8, w);
      }

  // ho fragments (k4 part, per batch)
  short8 bwh[4], bwl[4];
  #pragma unroll
  for (int nt = 0; nt < 4; ++nt){
    const size_t off = ((size_t)b*DD + l15 + 16*nt)*EE + 8*lg;
    bwh[nt] = *reinterpret_cast<const short8*>(ho_hi + off);
    bwl[nt] = *reinterpret_cast<const short8*>(ho_lo + off);
  }

  float b1c[4], b2c[4], g1c[4], B1c[4], g2c[4], B2c[4];
  #pragma unroll
  for (int nt = 0; nt < 4; ++nt){
    b1c[nt] = b1[l15 + 16*nt];
    b2c[nt] = b2[l15 + 16*nt];
    g1c[nt] = lng[l15 + 16*nt];
    B1c[nt] = lnb[l15 + 16*nt];
    g2c[nt] = hg[l15 + 16*nt];
    B2c[nt] = hb[l15 + 16*nt];
  }

  const int tpb = MM / 16;                      // 768 tiles per batch; 2 tiles/wave at CPB4=96
  for (int tl = blk*4 + wid; tl < tpb; tl += CPB4*4){
    const size_t r0 = (size_t)b*MM + (size_t)tl*16;  // global row base
    const int t = (tl*16) >> 10;                // local frame index 0..11

    // ---- k1-part A-fragments ----
    const float* pc = x + (r0 + l15)*DD + k0;
    float4 a00 = *reinterpret_cast<const float4*>(pc);
    float4 a01 = *reinterpret_cast<const float4*>(pc + 4);
    float4 a10 = *reinterpret_cast<const float4*>(pc + 32);
    float4 a11 = *reinterpret_cast<const float4*>(pc + 36);
    if (t > 0){
      const float* pp = pc - (size_t)NN*DD;
      const float4 q00 = *reinterpret_cast<const float4*>(pp);
      const float4 q01 = *reinterpret_cast<const float4*>(pp + 4);
      const float4 q10 = *reinterpret_cast<const float4*>(pp + 32);
      const float4 q11 = *reinterpret_cast<const float4*>(pp + 36);
      a00.x = 0.5f*(a00.x+q00.x); a00.y = 0.5f*(a00.y+q00.y);
      a00.z = 0.5f*(a00.z+q00.z); a00.w = 0.5f*(a00.w+q00.w);
      a01.x = 0.5f*(a01.x+q01.x); a01.y = 0.5f*(a01.y+q01.y);
      a01.z = 0.5f*(a01.z+q01.z); a01.w = 0.5f*(a01.w+q01.w);
      a10.x = 0.5f*(a10.x+q10.x); a10.y = 0.5f*(a10.y+q10.y);
      a10.z = 0.5f*(a10.z+q10.z); a10.w = 0.5f*(a10.w+q10.w);
      a11.x = 0.5f*(a11.x+q11.x); a11.y = 0.5f*(a11.y+q11.y);
      a11.z = 0.5f*(a11.z+q11.z); a11.w = 0.5f*(a11.w+q11.w);
    } else {
      a00.x*=0.5f;a00.y*=0.5f;a00.z*=0.5f;a00.w*=0.5f;
      a01.x*=0.5f;a01.y*=0.5f;a01.z*=0.5f;a01.w*=0.5f;
      a10.x*=0.5f;a10.y*=0.5f;a10.z*=0.5f;a10.w*=0.5f;
      a11.x*=0.5f;a11.y*=0.5f;a11.z*=0.5f;a11.w*=0.5f;
    }
    // shared epilogue x loads (C-layout rows)
    float epi[4][4];
    #pragma unroll
    for (int q = 0; q < 4; ++q){
      const float* pr = x + (r0 + 4*lg + q)*DD + l15;
      #pragma unroll
      for (int nt = 0; nt < 4; ++nt) epi[q][nt] = pr[16*nt];
    }
    // k4-part A-fragments
    const short8 afh = *reinterpret_cast<const short8*>(assign_hi + (r0 + l15)*EE + 8*lg);
    const short8 afl = *reinterpret_cast<const short8*>(assign_lo + (r0 + l15)*EE + 8*lg);

    short8 af[2];
    {
      int4v w;
      w.x = cvt2(a00.x, a00.y); w.y = cvt2(a00.z, a00.w);
      w.z = cvt2(a01.x, a01.y); w.w = cvt2(a01.z, a01.w);
      af[0] = __builtin_bit_cast(short8, w);
      w.x = cvt2(a10.x, a10.y); w.y = cvt2(a10.z, a10.w);
      w.z = cvt2(a11.x, a11.y); w.w = cvt2(a11.z, a11.w);
      af[1] = __builtin_bit_cast(short8, w);
    }

    f32x4 acc1[2][4], acc4[4];
    #pragma unroll
    for (int m = 0; m < 2; ++m)
      #pragma unroll
      for (int nt = 0; nt < 4; ++nt) acc1[m][nt] = (f32x4){0.f,0.f,0.f,0.f};
    #pragma unroll
    for (int nt = 0; nt < 4; ++nt) acc4[nt] = (f32x4){0.f,0.f,0.f,0.f};

    #pragma unroll
    for (int kc = 0; kc < 2; ++kc){
      #pragma unroll
      for (int nt = 0; nt < 4; ++nt){
        acc1[0][nt] = __builtin_amdgcn_mfma_f32_16x16x32_bf16(af[kc], bw[0][nt][kc], acc1[0][nt], 0, 0, 0);
        acc1[1][nt] = __builtin_amdgcn_mfma_f32_16x16x32_bf16(af[kc], bw[1][nt][kc], acc1[1][nt], 0, 0, 0);
      }
    }
    #pragma unroll
    for (int nt = 0; nt < 4; ++nt){
      acc4[nt] = __builtin_amdgcn_mfma_f32_16x16x32_bf16(afh, bwh[nt], acc4[nt], 0, 0, 0);
      acc4[nt] = __builtin_amdgcn_mfma_f32_16x16x32_bf16(afh, bwl[nt], acc4[nt], 0, 0, 0);
      acc4[nt] = __builtin_amdgcn_mfma_f32_16x16x32_bf16(afl, bwh[nt], acc4[nt], 0, 0, 0);
    }

    // ---- dual epilogue: LN1 (stgcn) and LN2 (hyper), interleaved shfl chains ----
    #pragma unroll
    for (int q = 0; q < 4; ++q){
      const size_t row = r0 + 4*lg + q;
      float s1[4], s2[4];
      float rs1 = 0.f, rs2 = 0.f;
      #pragma unroll
      for (int nt = 0; nt < 4; ++nt){
        const float g1 = acc1[0][nt][q] + b1c[nt];
        const float g2 = acc1[1][nt][q] + b2c[nt];
        s1[nt] = fmaxf(g1*g2, 0.f) + g1 + epi[q][nt];
        rs1 += s1[nt];
        s2[nt] = fmaxf(acc4[nt][q], 0.f) + epi[q][nt];
        rs2 += s2[nt];
      }
      #pragma unroll
      for (int off = 8; off; off >>= 1){ rs1 += __shfl_xor(rs1, off); rs2 += __shfl_xor(rs2, off); }
      const float m1 = rs1 * (1.f/DD);
      const float m2 = rs2 * (1.f/DD);
      float d1[4], d2[4]; float v1 = 0.f, v2 = 0.f;
      #pragma unroll
      for (int nt = 0; nt < 4; ++nt){
        d1[nt] = s1[nt] - m1; v1 = fmaf(d1[nt], d1[nt], v1);
        d2[nt] = s2[nt] - m2; v2 = fmaf(d2[nt], d2[nt], v2);
      }
      #pragma unroll
      for (int off = 8; off; off >>= 1){ v1 += __shfl_xor(v1, off); v2 += __shfl_xor(v2, off); }
      const float i1 = rsqrtf(v1 * (1.f/DD) + LN_EPS);
      const float i2 = rsqrtf(v2 * (1.f/DD) + LN_EPS);
      #pragma unroll
      for (int nt = 0; nt < 4; ++nt){
        const float o1 = d1[nt]*i1*g1c[nt] + B1c[nt];
        const float o2 = d2[nt]*i2*g2c[nt] + B2c[nt];
        xout[row*DD + l15 + 16*nt] = 0.5f*(o1 + o2);
      }
    }
  }
}

extern "C" void kernel_launch(void* const* d_in, const int* in_sizes, int n_in,
                              void* d_out, int out_size, void* d_ws, size_t ws_size,
                              hipStream_t stream)
{
  (void)in_sizes; (void)n_in; (void)out_size; (void)ws_size;
  const float* x0  = (const float*)d_in[0];
  const float* W1  = (const float*)d_in[1];
  const float* b1  = (const float*)d_in[2];
  const float* W2  = (const float*)d_in[3];
  const float* b2  = (const float*)d_in[4];
  const float* lng = (const float*)d_in[5];
  const float* lnb = (const float*)d_in[6];
  const float* clf = (const float*)d_in[7];
  const float* em  = (const float*)d_in[8];
  const float* hg  = (const float*)d_in[9];
  const float* hb  = (const float*)d_in[10];
  float* out = (float*)d_out;

  // workspace: x ping f32 | hf_part f32 [BB][CPB2N][EE*DD] (12.6 MB) | assign hi/lo bf16 | ho hi/lo bf16
  float* ws_x = (float*)d_ws;
  float* hf_part = ws_x + (size_t)ROWS*DD;
  unsigned short* assign_hi = (unsigned short*)(hf_part + (size_t)BB*CPB2N*EE*DD);
  unsigned short* assign_lo = assign_hi + (size_t)ROWS*EE;
  unsigned short* ho_hi     = assign_lo + (size_t)ROWS*EE;
  unsigned short* ho_lo     = ho_hi + (size_t)BB*DD*EE;

  // ping-pong so xin != xout at EVERY depth (k14 reads t-1 rows cross-tile):
  // depth 0: x0 -> d_out ; depth 1: d_out -> ws_x ; depth 2: ws_x -> d_out (final)
  const float* xin_seq[3]  = { x0, out, ws_x };
  float*       xout_seq[3] = { out, ws_x, out };

  for (int i = 0; i < 3; ++i){
    const float* xin = xin_seq[i];
    float* xout = xout_seq[i];
    k2_hyper1<<<BB*CPB2N, 256, 0, stream>>>(xin, clf, assign_hi, assign_lo, hf_part);
    k3_edge<<<BB, 256, 0, stream>>>(hf_part, em, ho_hi, ho_lo);
    k14_fused<<<BB*CPB4, 256, 0, stream>>>(xin, W1 + i*DD*DD, b1 + i*DD,
                                           W2 + i*DD*DD, b2 + i*DD,
                                           lng + i*DD, lnb + i*DD,
                                           assign_hi, assign_lo, ho_hi, ho_lo,
                                           hg, hb, xout);
  }
}

// Round 15
// 263.595 us; speedup vs baseline: 1.5590x; 1.0899x over previous
//
#include <hip/hip_runtime.h>

#define BB 16
#define TT 12
#define NN 1024
#define DD 64
#define EE 32
#define MM (TT*NN)          // 12288 rows per batch
#define ROWS (BB*MM)        // 196608 total rows
#define CPB2N 96            // k2 blocks per batch -> grid 1536; 1 chunk/wave
#define S_ITER (384/(CPB2N*4))   // chunks per wave (384 chunks of 32 rows per batch)
#define CPB4 64             // k14 blocks per batch -> grid 1024 = exactly 4 blocks/CU, 3 tiles/wave (best measured)
#define LN_EPS 1e-5f

typedef __attribute__((ext_vector_type(8))) short short8;
typedef __attribute__((ext_vector_type(4))) float f32x4;
typedef __attribute__((ext_vector_type(4))) int   int4v;

// pack two f32 -> one dword of 2 bf16 (RNE), low = a, high = b
__device__ __forceinline__ int cvt2(float a, float b){
  int r;
  asm("v_cvt_pk_bf16_f32 %0, %1, %2" : "=v"(r) : "v"(a), "v"(b));
  return r;
}
__device__ __forceinline__ unsigned short bf16of(float a){
  return (unsigned short)(cvt2(a, a) & 0xffff);
}
__device__ __forceinline__ float f32of(unsigned short h){
  return __builtin_bit_cast(float, (unsigned int)h << 16);
}
__device__ __forceinline__ float lo16f(int w){ return __builtin_bit_cast(float, (unsigned int)w << 16); }
__device__ __forceinline__ float hi16f(int w){ return __builtin_bit_cast(float, (unsigned int)w & 0xffff0000u); }

__device__ __forceinline__ short8 pack_hi8(const float* v){
  int4v w;
  w.x = cvt2(v[0], v[1]); w.y = cvt2(v[2], v[3]);
  w.z = cvt2(v[4], v[5]); w.w = cvt2(v[6], v[7]);
  return __builtin_bit_cast(short8, w);
}
__device__ __forceinline__ short8 pack_lo8(const float* v, short8 hi){
  const int4v wh = __builtin_bit_cast(int4v, hi);
  float r[8];
  r[0] = v[0] - lo16f(wh.x); r[1] = v[1] - hi16f(wh.x);
  r[2] = v[2] - lo16f(wh.y); r[3] = v[3] - hi16f(wh.y);
  r[4] = v[4] - lo16f(wh.z); r[5] = v[5] - hi16f(wh.z);
  r[6] = v[6] - lo16f(wh.w); r[7] = v[7] - hi16f(wh.w);
  return pack_hi8(r);
}

// ---------------- K2: full-MFMA hyper stage 1 (round-7 body; chunk mapping generic in CPB2N) ----------------
__global__ __launch_bounds__(256, 3)
void k2_hyper1(const float* __restrict__ x, const float* __restrict__ clf,
               unsigned short* __restrict__ assign_hi, unsigned short* __restrict__ assign_lo,
               float* __restrict__ hf_part)
{
  __shared__ __align__(16) float lbuf[4224];   // union: amat 4x[32][33] | red 2x[32][65]
  const int lane = threadIdx.x & 63;
  const int wid  = threadIdx.x >> 6;
  const int l15  = lane & 15;
  const int lg   = lane >> 4;
  const int b    = blockIdx.x / CPB2N;
  const int blk  = blockIdx.x % CPB2N;
  float* amat = lbuf + wid*1056;               // [32][33] f32 per wave

  short8 bch[2][2], bcl[2][2];
  #pragma unroll
  for (int kc = 0; kc < 2; ++kc)
    #pragma unroll
    for (int nt = 0; nt < 2; ++nt){
      float v[8];
      #pragma unroll
      for (int j = 0; j < 8; ++j)
        v[j] = clf[(size_t)(32*kc + 8*lg + j)*EE + 16*nt + l15];
      bch[kc][nt] = pack_hi8(v);
      bcl[kc][nt] = pack_lo8(v, bch[kc][nt]);
    }

  f32x4 acc2[2][4];
  #pragma unroll
  for (int et = 0; et < 2; ++et)
    #pragma unroll
    for (int dt = 0; dt < 4; ++dt) acc2[et][dt] = (f32x4){0.f,0.f,0.f,0.f};

  const int wslot = blk*4 + wid;               // 0..CPB2N*4-1
  #pragma unroll 1
  for (int s = 0; s < S_ITER; ++s){
    const int c = wslot + s*(CPB2N*4);         // chunk id, covers 0..383 exactly once
    const size_t grb = (size_t)b*MM + (size_t)c*32;

    #pragma unroll 1
    for (int h = 0; h < 2; ++h){
      short8 axh[2], axl[2];
      #pragma unroll
      for (int kc = 0; kc < 2; ++kc){
        const float* p = x + (grb + 16*h + l15)*DD + 32*kc + 8*lg;
        float v[8];
        const float4 p0 = *reinterpret_cast<const float4*>(p);
        const float4 p1 = *reinterpret_cast<const float4*>(p + 4);
        v[0]=p0.x; v[1]=p0.y; v[2]=p0.z; v[3]=p0.w;
        v[4]=p1.x; v[5]=p1.y; v[6]=p1.z; v[7]=p1.w;
        axh[kc] = pack_hi8(v); axl[kc] = pack_lo8(v, axh[kc]);
      }
      f32x4 accL[2] = {(f32x4){0.f,0.f,0.f,0.f},(f32x4){0.f,0.f,0.f,0.f}};
      #pragma unroll
      for (int kc = 0; kc < 2; ++kc)
        #pragma unroll
        for (int nt = 0; nt < 2; ++nt){
          accL[nt] = __builtin_amdgcn_mfma_f32_16x16x32_bf16(axh[kc], bch[kc][nt], accL[nt], 0, 0, 0);
          accL[nt] = __builtin_amdgcn_mfma_f32_16x16x32_bf16(axh[kc], bcl[kc][nt], accL[nt], 0, 0, 0);
          accL[nt] = __builtin_amdgcn_mfma_f32_16x16x32_bf16(axl[kc], bch[kc][nt], accL[nt], 0, 0, 0);
        }
      #pragma unroll
      for (int q = 0; q < 4; ++q){
        const float l0 = accL[0][q], l1 = accL[1][q];
        float mx = fmaxf(l0, l1);
        #pragma unroll
        for (int off = 8; off; off >>= 1) mx = fmaxf(mx, __shfl_xor(mx, off));
        const float e0 = expf(l0 - mx), e1 = expf(l1 - mx);
        float sm = e0 + e1;
        #pragma unroll
        for (int off = 8; off; off >>= 1) sm += __shfl_xor(sm, off);
        const float inv = 1.f / sm;
        const float a0 = e0*inv, a1 = e1*inv;
        const int rloc = 16*h + 4*lg + q;
        const size_t row = grb + rloc;
        const unsigned short h0 = bf16of(a0);
        const unsigned short h1 = bf16of(a1);
        assign_hi[row*EE + l15]      = h0;
        assign_hi[row*EE + 16 + l15] = h1;
        assign_lo[row*EE + l15]      = bf16of(a0 - f32of(h0));
        assign_lo[row*EE + 16 + l15] = bf16of(a1 - f32of(h1));
        amat[rloc*33 + l15]      = a0;
        amat[rloc*33 + 16 + l15] = a1;
      }
    }
    __builtin_amdgcn_wave_barrier();
    short8 a2h[2], a2l[2];
    #pragma unroll
    for (int et = 0; et < 2; ++et){
      float v[8];
      #pragma unroll
      for (int j = 0; j < 8; ++j)
        v[j] = amat[(8*lg + j)*33 + 16*et + l15];
      a2h[et] = pack_hi8(v); a2l[et] = pack_lo8(v, a2h[et]);
    }
    #pragma unroll
    for (int dt = 0; dt < 4; ++dt){
      float v[8];
      #pragma unroll
      for (int j = 0; j < 8; ++j)
        v[j] = x[(grb + 8*lg + j)*DD + 16*dt + l15];
      const short8 b2 = pack_hi8(v);
      #pragma unroll
      for (int et = 0; et < 2; ++et){
        acc2[et][dt] = __builtin_amdgcn_mfma_f32_16x16x32_bf16(a2h[et], b2, acc2[et][dt], 0, 0, 0);
        acc2[et][dt] = __builtin_amdgcn_mfma_f32_16x16x32_bf16(a2l[et], b2, acc2[et][dt], 0, 0, 0);
      }
    }
    __builtin_amdgcn_wave_barrier();
  }

  __syncthreads();
  float* red = lbuf;
  if (wid < 2){
    #pragma unroll
    for (int et = 0; et < 2; ++et)
      #pragma unroll
      for (int dt = 0; dt < 4; ++dt)
        #pragma unroll
        for (int q = 0; q < 4; ++q)
          red[wid*2080 + (16*et + 4*lg + q)*65 + 16*dt + l15] = acc2[et][dt][q];
  }
  __syncthreads();
  if (wid >= 2){
    #pragma unroll
    for (int et = 0; et < 2; ++et)
      #pragma unroll
      for (int dt = 0; dt < 4; ++dt)
        #pragma unroll
        for (int q = 0; q < 4; ++q)
          red[(wid-2)*2080 + (16*et + 4*lg + q)*65 + 16*dt + l15] += acc2[et][dt][q];
  }
  __syncthreads();
  float* dst = hf_part + ((size_t)b*CPB2N + blk)*(EE*DD);
  for (int i = threadIdx.x; i < EE*DD; i += 256){
    const int e = i >> 6, d = i & 63;
    dst[i] = red[e*65 + d] + red[2080 + e*65 + d];
  }
}

// ---------------- K3: sum hf_part slots; ho = relu(em @ hf) + hf; emit transposed bf16 hi/lo ----------------
__global__ void k3_edge(const float* __restrict__ hf_part, const float* __restrict__ em,
                        unsigned short* __restrict__ ho_hi, unsigned short* __restrict__ ho_lo)
{
  __shared__ float ems[EE*EE];
  __shared__ float hfs[EE*DD];
  const int b = blockIdx.x;
  const int tid = threadIdx.x;
  for (int i = tid; i < EE*EE; i += 256) ems[i] = em[i];
  for (int i = tid; i < EE*DD; i += 256){
    const float* p = hf_part + (size_t)b*CPB2N*(EE*DD) + i;
    float s0=0.f, s1=0.f, s2=0.f, s3=0.f;
    #pragma unroll
    for (int k = 0; k < CPB2N; k += 4){
      s0 += p[(size_t)(k+0)*EE*DD]; s1 += p[(size_t)(k+1)*EE*DD];
      s2 += p[(size_t)(k+2)*EE*DD]; s3 += p[(size_t)(k+3)*EE*DD];
    }
    hfs[i] = (s0+s1)+(s2+s3);
  }
  __syncthreads();
  for (int i = tid; i < EE*DD; i += 256){
    const int e = i >> 6, d = i & 63;
    float acc = 0.f;
    #pragma unroll
    for (int f = 0; f < EE; ++f) acc = fmaf(ems[e*EE+f], hfs[f*DD+d], acc);
    const float v = fmaxf(acc, 0.f) + hfs[e*DD+d];
    const unsigned short hi = bf16of(v);
    const unsigned short lo = bf16of(v - f32of(hi));
    ho_hi[((size_t)b*DD + d)*EE + e] = hi;
    ho_lo[((size_t)b*DD + d)*EE + e] = lo;
  }
}

// ---------------- K14: fused STGCN + hyper-combine per tile (no out1 buffer) ----------------
// REQUIRES xin != xout (launcher ping-pongs): reads x[t-1] rows cross-tile.
__global__ __launch_bounds__(256, 2)
void k14_fused(const float* __restrict__ x,
               const float* __restrict__ W1, const float* __restrict__ b1,
               const float* __restrict__ W2, const float* __restrict__ b2,
               const float* __restrict__ lng, const float* __restrict__ lnb,
               const unsigned short* __restrict__ assign_hi,
               const unsigned short* __restrict__ assign_lo,
               const unsigned short* __restrict__ ho_hi,
               const unsigned short* __restrict__ ho_lo,
               const float* __restrict__ hg, const float* __restrict__ hb,
               float* __restrict__ xout)
{
  const int lane = threadIdx.x & 63;
  const int wid  = threadIdx.x >> 6;
  const int b    = blockIdx.x / CPB4;
  const int blk  = blockIdx.x % CPB4;
  const int l15  = lane & 15;
  const int lg   = lane >> 4;
  const int k0   = lg * 8;

  // W fragments (k1 part)
  short8 bw[2][4][2];
  const float* Wm[2] = {W1, W2};
  #pragma unroll
  for (int m = 0; m < 2; ++m)
    #pragma unroll
    for (int nt = 0; nt < 4; ++nt)
      #pragma unroll
      for (int kc = 0; kc < 2; ++kc){
        const float* src = Wm[m] + (size_t)(16*nt + l15)*DD + 32*kc + k0;
        const float4 p0 = *reinterpret_cast<const float4*>(src);
        const float4 p1 = *reinterpret_cast<const float4*>(src + 4);
        int4v w;
        w.x = cvt2(p0.x, p0.y); w.y = cvt2(p0.z, p0.w);
        w.z = cvt2(p1.x, p1.y); w.w = cvt2(p1.z, p1.w);
        bw[m][nt][kc] = __builtin_bit_cast(short8, w);
      }

  // ho fragments (k4 part, per batch)
  short8 bwh[4], bwl[4];
  #pragma unroll
  for (int nt = 0; nt < 4; ++nt){
    const size_t off = ((size_t)b*DD + l15 + 16*nt)*EE + 8*lg;
    bwh[nt] = *reinterpret_cast<const short8*>(ho_hi + off);
    bwl[nt] = *reinterpret_cast<const short8*>(ho_lo + off);
  }

  float b1c[4], b2c[4], g1c[4], B1c[4], g2c[4], B2c[4];
  #pragma unroll
  for (int nt = 0; nt < 4; ++nt){
    b1c[nt] = b1[l15 + 16*nt];
    b2c[nt] = b2[l15 + 16*nt];
    g1c[nt] = lng[l15 + 16*nt];
    B1c[nt] = lnb[l15 + 16*nt];
    g2c[nt] = hg[l15 + 16*nt];
    B2c[nt] = hb[l15 + 16*nt];
  }

  const int tpb = MM / 16;                      // 768 tiles per batch; 3 tiles/wave at CPB4=64
  for (int tl = blk*4 + wid; tl < tpb; tl += CPB4*4){
    const size_t r0 = (size_t)b*MM + (size_t)tl*16;  // global row base
    const int t = (tl*16) >> 10;                // local frame index 0..11

    // ---- k1-part A-fragments ----
    const float* pc = x + (r0 + l15)*DD + k0;
    float4 a00 = *reinterpret_cast<const float4*>(pc);
    float4 a01 = *reinterpret_cast<const float4*>(pc + 4);
    float4 a10 = *reinterpret_cast<const float4*>(pc + 32);
    float4 a11 = *reinterpret_cast<const float4*>(pc + 36);
    if (t > 0){
      const float* pp = pc - (size_t)NN*DD;
      const float4 q00 = *reinterpret_cast<const float4*>(pp);
      const float4 q01 = *reinterpret_cast<const float4*>(pp + 4);
      const float4 q10 = *reinterpret_cast<const float4*>(pp + 32);
      const float4 q11 = *reinterpret_cast<const float4*>(pp + 36);
      a00.x = 0.5f*(a00.x+q00.x); a00.y = 0.5f*(a00.y+q00.y);
      a00.z = 0.5f*(a00.z+q00.z); a00.w = 0.5f*(a00.w+q00.w);
      a01.x = 0.5f*(a01.x+q01.x); a01.y = 0.5f*(a01.y+q01.y);
      a01.z = 0.5f*(a01.z+q01.z); a01.w = 0.5f*(a01.w+q01.w);
      a10.x = 0.5f*(a10.x+q10.x); a10.y = 0.5f*(a10.y+q10.y);
      a10.z = 0.5f*(a10.z+q10.z); a10.w = 0.5f*(a10.w+q10.w);
      a11.x = 0.5f*(a11.x+q11.x); a11.y = 0.5f*(a11.y+q11.y);
      a11.z = 0.5f*(a11.z+q11.z); a11.w = 0.5f*(a11.w+q11.w);
    } else {
      a00.x*=0.5f;a00.y*=0.5f;a00.z*=0.5f;a00.w*=0.5f;
      a01.x*=0.5f;a01.y*=0.5f;a01.z*=0.5f;a01.w*=0.5f;
      a10.x*=0.5f;a10.y*=0.5f;a10.z*=0.5f;a10.w*=0.5f;
      a11.x*=0.5f;a11.y*=0.5f;a11.z*=0.5f;a11.w*=0.5f;
    }
    // shared epilogue x loads (C-layout rows)
    float epi[4][4];
    #pragma unroll
    for (int q = 0; q < 4; ++q){
      const float* pr = x + (r0 + 4*lg + q)*DD + l15;
      #pragma unroll
      for (int nt = 0; nt < 4; ++nt) epi[q][nt] = pr[16*nt];
    }
    // k4-part A-fragments
    const short8 afh = *reinterpret_cast<const short8*>(assign_hi + (r0 + l15)*EE + 8*lg);
    const short8 afl = *reinterpret_cast<const short8*>(assign_lo + (r0 + l15)*EE + 8*lg);

    short8 af[2];
    {
      int4v w;
      w.x = cvt2(a00.x, a00.y); w.y = cvt2(a00.z, a00.w);
      w.z = cvt2(a01.x, a01.y); w.w = cvt2(a01.z, a01.w);
      af[0] = __builtin_bit_cast(short8, w);
      w.x = cvt2(a10.x, a10.y); w.y = cvt2(a10.z, a10.w);
      w.z = cvt2(a11.x, a11.y); w.w = cvt2(a11.z, a11.w);
      af[1] = __builtin_bit_cast(short8, w);
    }

    f32x4 acc1[2][4], acc4[4];
    #pragma unroll
    for (int m = 0; m < 2; ++m)
      #pragma unroll
      for (int nt = 0; nt < 4; ++nt) acc1[m][nt] = (f32x4){0.f,0.f,0.f,0.f};
    #pragma unroll
    for (int nt = 0; nt < 4; ++nt) acc4[nt] = (f32x4){0.f,0.f,0.f,0.f};

    #pragma unroll
    for (int kc = 0; kc < 2; ++kc){
      #pragma unroll
      for (int nt = 0; nt < 4; ++nt){
        acc1[0][nt] = __builtin_amdgcn_mfma_f32_16x16x32_bf16(af[kc], bw[0][nt][kc], acc1[0][nt], 0, 0, 0);
        acc1[1][nt] = __builtin_amdgcn_mfma_f32_16x16x32_bf16(af[kc], bw[1][nt][kc], acc1[1][nt], 0, 0, 0);
      }
    }
    #pragma unroll
    for (int nt = 0; nt < 4; ++nt){
      acc4[nt] = __builtin_amdgcn_mfma_f32_16x16x32_bf16(afh, bwh[nt], acc4[nt], 0, 0, 0);
      acc4[nt] = __builtin_amdgcn_mfma_f32_16x16x32_bf16(afh, bwl[nt], acc4[nt], 0, 0, 0);
      acc4[nt] = __builtin_amdgcn_mfma_f32_16x16x32_bf16(afl, bwh[nt], acc4[nt], 0, 0, 0);
    }

    // ---- dual epilogue: LN1 (stgcn) and LN2 (hyper), interleaved shfl chains ----
    #pragma unroll
    for (int q = 0; q < 4; ++q){
      const size_t row = r0 + 4*lg + q;
      float s1[4], s2[4];
      float rs1 = 0.f, rs2 = 0.f;
      #pragma unroll
      for (int nt = 0; nt < 4; ++nt){
        const float g1 = acc1[0][nt][q] + b1c[nt];
        const float g2 = acc1[1][nt][q] + b2c[nt];
        s1[nt] = fmaxf(g1*g2, 0.f) + g1 + epi[q][nt];
        rs1 += s1[nt];
        s2[nt] = fmaxf(acc4[nt][q], 0.f) + epi[q][nt];
        rs2 += s2[nt];
      }
      #pragma unroll
      for (int off = 8; off; off >>= 1){ rs1 += __shfl_xor(rs1, off); rs2 += __shfl_xor(rs2, off); }
      const float m1 = rs1 * (1.f/DD);
      const float m2 = rs2 * (1.f/DD);
      float d1[4], d2[4]; float v1 = 0.f, v2 = 0.f;
      #pragma unroll
      for (int nt = 0; nt < 4; ++nt){
        d1[nt] = s1[nt] - m1; v1 = fmaf(d1[nt], d1[nt], v1);
        d2[nt] = s2[nt] - m2; v2 = fmaf(d2[nt], d2[nt], v2);
      }
      #pragma unroll
      for (int off = 8; off; off >>= 1){ v1 += __shfl_xor(v1, off); v2 += __shfl_xor(v2, off); }
      const float i1 = rsqrtf(v1 * (1.f/DD) + LN_EPS);
      const float i2 = rsqrtf(v2 * (1.f/DD) + LN_EPS);
      #pragma unroll
      for (int nt = 0; nt < 4; ++nt){
        const float o1 = d1[nt]*i1*g1c[nt] + B1c[nt];
        const float o2 = d2[nt]*i2*g2c[nt] + B2c[nt];
        xout[row*DD + l15 + 16*nt] = 0.5f*(o1 + o2);
      }
    }
  }
}

extern "C" void kernel_launch(void* const* d_in, const int* in_sizes, int n_in,
                              void* d_out, int out_size, void* d_ws, size_t ws_size,
                              hipStream_t stream)
{
  (void)in_sizes; (void)n_in; (void)out_size; (void)ws_size;
  const float* x0  = (const float*)d_in[0];
  const float* W1  = (const float*)d_in[1];
  const float* b1  = (const float*)d_in[2];
  const float* W2  = (const float*)d_in[3];
  const float* b2  = (const float*)d_in[4];
  const float* lng = (const float*)d_in[5];
  const float* lnb = (const float*)d_in[6];
  const float* clf = (const float*)d_in[7];
  const float* em  = (const float*)d_in[8];
  const float* hg  = (const float*)d_in[9];
  const float* hb  = (const float*)d_in[10];
  float* out = (float*)d_out;

  // workspace: x ping f32 | hf_part f32 [BB][CPB2N][EE*DD] (12.6 MB) | assign hi/lo bf16 | ho hi/lo bf16
  float* ws_x = (float*)d_ws;
  float* hf_part = ws_x + (size_t)ROWS*DD;
  unsigned short* assign_hi = (unsigned short*)(hf_part + (size_t)BB*CPB2N*EE*DD);
  unsigned short* assign_lo = assign_hi + (size_t)ROWS*EE;
  unsigned short* ho_hi     = assign_lo + (size_t)ROWS*EE;
  unsigned short* ho_lo     = ho_hi + (size_t)BB*DD*EE;

  // ping-pong so xin != xout at EVERY depth (k14 reads t-1 rows cross-tile):
  // depth 0: x0 -> d_out ; depth 1: d_out -> ws_x ; depth 2: ws_x -> d_out (final)
  const float* xin_seq[3]  = { x0, out, ws_x };
  float*       xout_seq[3] = { out, ws_x, out };

  for (int i = 0; i < 3; ++i){
    const float* xin = xin_seq[i];
    float* xout = xout_seq[i];
    k2_hyper1<<<BB*CPB2N, 256, 0, stream>>>(xin, clf, assign_hi, assign_lo, hf_part);
    k3_edge<<<BB, 256, 0, stream>>>(hf_part, em, ho_hi, ho_lo);
    k14_fused<<<BB*CPB4, 256, 0, stream>>>(xin, W1 + i*DD*DD, b1 + i*DD,
                                           W2 + i*DD*DD, b2 + i*DD,
                                           lng + i*DD, lnb + i*DD,
                                           assign_hi, assign_lo, ho_hi, ho_lo,
                                           hg, hb, xout);
  }
}

// Round 16
// 224.149 us; speedup vs baseline: 1.8334x; 1.1760x over previous
//
#include <hip/hip_runtime.h>

#define BB 16
#define TT 12
#define NN 1024
#define DD 64
#define EE 32
#define MM (TT*NN)          // 12288 rows per batch
#define ROWS (BB*MM)        // 196608 total rows
#define CPB2N 96            // k2 blocks per batch -> grid 1536; 1 chunk/wave
#define S_ITER (384/(CPB2N*4))   // chunks per wave
#define CPB4 64             // k14 blocks per batch -> grid 1024 = exactly 4 blocks/CU, 3 tiles/wave
#define LN_EPS 1e-5f

typedef __attribute__((ext_vector_type(8))) short short8;
typedef __attribute__((ext_vector_type(4))) float f32x4;
typedef __attribute__((ext_vector_type(4))) int   int4v;

// pack two f32 -> one dword of 2 bf16 (RNE), low = a, high = b
__device__ __forceinline__ int cvt2(float a, float b){
  int r;
  asm("v_cvt_pk_bf16_f32 %0, %1, %2" : "=v"(r) : "v"(a), "v"(b));
  return r;
}
__device__ __forceinline__ unsigned short bf16of(float a){
  return (unsigned short)(cvt2(a, a) & 0xffff);
}
__device__ __forceinline__ float f32of(unsigned short h){
  return __builtin_bit_cast(float, (unsigned int)h << 16);
}
__device__ __forceinline__ float lo16f(int w){ return __builtin_bit_cast(float, (unsigned int)w << 16); }
__device__ __forceinline__ float hi16f(int w){ return __builtin_bit_cast(float, (unsigned int)w & 0xffff0000u); }

__device__ __forceinline__ short8 pack_hi8(const float* v){
  int4v w;
  w.x = cvt2(v[0], v[1]); w.y = cvt2(v[2], v[3]);
  w.z = cvt2(v[4], v[5]); w.w = cvt2(v[6], v[7]);
  return __builtin_bit_cast(short8, w);
}
__device__ __forceinline__ short8 pack_lo8(const float* v, short8 hi){
  const int4v wh = __builtin_bit_cast(int4v, hi);
  float r[8];
  r[0] = v[0] - lo16f(wh.x); r[1] = v[1] - hi16f(wh.x);
  r[2] = v[2] - lo16f(wh.y); r[3] = v[3] - hi16f(wh.y);
  r[4] = v[4] - lo16f(wh.z); r[5] = v[5] - hi16f(wh.z);
  r[6] = v[6] - lo16f(wh.w); r[7] = v[7] - hi16f(wh.w);
  return pack_hi8(r);
}

// ---------------- K2: full-MFMA hyper stage 1; finishes with atomicAdd into hf (round-6-proven) ----------------
__global__ __launch_bounds__(256, 3)
void k2_hyper1(const float* __restrict__ x, const float* __restrict__ clf,
               unsigned short* __restrict__ assign_hi, unsigned short* __restrict__ assign_lo,
               float* __restrict__ hf)
{
  __shared__ __align__(16) float lbuf[4224];   // union: amat 4x[32][33] | red 2x[32][65]
  const int lane = threadIdx.x & 63;
  const int wid  = threadIdx.x >> 6;
  const int l15  = lane & 15;
  const int lg   = lane >> 4;
  const int b    = blockIdx.x / CPB2N;
  const int blk  = blockIdx.x % CPB2N;
  float* amat = lbuf + wid*1056;               // [32][33] f32 per wave

  short8 bch[2][2], bcl[2][2];
  #pragma unroll
  for (int kc = 0; kc < 2; ++kc)
    #pragma unroll
    for (int nt = 0; nt < 2; ++nt){
      float v[8];
      #pragma unroll
      for (int j = 0; j < 8; ++j)
        v[j] = clf[(size_t)(32*kc + 8*lg + j)*EE + 16*nt + l15];
      bch[kc][nt] = pack_hi8(v);
      bcl[kc][nt] = pack_lo8(v, bch[kc][nt]);
    }

  f32x4 acc2[2][4];
  #pragma unroll
  for (int et = 0; et < 2; ++et)
    #pragma unroll
    for (int dt = 0; dt < 4; ++dt) acc2[et][dt] = (f32x4){0.f,0.f,0.f,0.f};

  const int wslot = blk*4 + wid;               // 0..CPB2N*4-1
  #pragma unroll 1
  for (int s = 0; s < S_ITER; ++s){
    const int c = wslot + s*(CPB2N*4);         // chunk id, covers 0..383 exactly once
    const size_t grb = (size_t)b*MM + (size_t)c*32;

    #pragma unroll 1
    for (int h = 0; h < 2; ++h){
      short8 axh[2], axl[2];
      #pragma unroll
      for (int kc = 0; kc < 2; ++kc){
        const float* p = x + (grb + 16*h + l15)*DD + 32*kc + 8*lg;
        float v[8];
        const float4 p0 = *reinterpret_cast<const float4*>(p);
        const float4 p1 = *reinterpret_cast<const float4*>(p + 4);
        v[0]=p0.x; v[1]=p0.y; v[2]=p0.z; v[3]=p0.w;
        v[4]=p1.x; v[5]=p1.y; v[6]=p1.z; v[7]=p1.w;
        axh[kc] = pack_hi8(v); axl[kc] = pack_lo8(v, axh[kc]);
      }
      f32x4 accL[2] = {(f32x4){0.f,0.f,0.f,0.f},(f32x4){0.f,0.f,0.f,0.f}};
      #pragma unroll
      for (int kc = 0; kc < 2; ++kc)
        #pragma unroll
        for (int nt = 0; nt < 2; ++nt){
          accL[nt] = __builtin_amdgcn_mfma_f32_16x16x32_bf16(axh[kc], bch[kc][nt], accL[nt], 0, 0, 0);
          accL[nt] = __builtin_amdgcn_mfma_f32_16x16x32_bf16(axh[kc], bcl[kc][nt], accL[nt], 0, 0, 0);
          accL[nt] = __builtin_amdgcn_mfma_f32_16x16x32_bf16(axl[kc], bch[kc][nt], accL[nt], 0, 0, 0);
        }
      #pragma unroll
      for (int q = 0; q < 4; ++q){
        const float l0 = accL[0][q], l1 = accL[1][q];
        float mx = fmaxf(l0, l1);
        #pragma unroll
        for (int off = 8; off; off >>= 1) mx = fmaxf(mx, __shfl_xor(mx, off));
        const float e0 = expf(l0 - mx), e1 = expf(l1 - mx);
        float sm = e0 + e1;
        #pragma unroll
        for (int off = 8; off; off >>= 1) sm += __shfl_xor(sm, off);
        const float inv = 1.f / sm;
        const float a0 = e0*inv, a1 = e1*inv;
        const int rloc = 16*h + 4*lg + q;
        const size_t row = grb + rloc;
        const unsigned short h0 = bf16of(a0);
        const unsigned short h1 = bf16of(a1);
        assign_hi[row*EE + l15]      = h0;
        assign_hi[row*EE + 16 + l15] = h1;
        assign_lo[row*EE + l15]      = bf16of(a0 - f32of(h0));
        assign_lo[row*EE + 16 + l15] = bf16of(a1 - f32of(h1));
        amat[rloc*33 + l15]      = a0;
        amat[rloc*33 + 16 + l15] = a1;
      }
    }
    __builtin_amdgcn_wave_barrier();
    short8 a2h[2], a2l[2];
    #pragma unroll
    for (int et = 0; et < 2; ++et){
      float v[8];
      #pragma unroll
      for (int j = 0; j < 8; ++j)
        v[j] = amat[(8*lg + j)*33 + 16*et + l15];
      a2h[et] = pack_hi8(v); a2l[et] = pack_lo8(v, a2h[et]);
    }
    #pragma unroll
    for (int dt = 0; dt < 4; ++dt){
      float v[8];
      #pragma unroll
      for (int j = 0; j < 8; ++j)
        v[j] = x[(grb + 8*lg + j)*DD + 16*dt + l15];
      const short8 b2 = pack_hi8(v);
      #pragma unroll
      for (int et = 0; et < 2; ++et){
        acc2[et][dt] = __builtin_amdgcn_mfma_f32_16x16x32_bf16(a2h[et], b2, acc2[et][dt], 0, 0, 0);
        acc2[et][dt] = __builtin_amdgcn_mfma_f32_16x16x32_bf16(a2l[et], b2, acc2[et][dt], 0, 0, 0);
      }
    }
    __builtin_amdgcn_wave_barrier();
  }

  __syncthreads();
  float* red = lbuf;
  if (wid < 2){
    #pragma unroll
    for (int et = 0; et < 2; ++et)
      #pragma unroll
      for (int dt = 0; dt < 4; ++dt)
        #pragma unroll
        for (int q = 0; q < 4; ++q)
          red[wid*2080 + (16*et + 4*lg + q)*65 + 16*dt + l15] = acc2[et][dt][q];
  }
  __syncthreads();
  if (wid >= 2){
    #pragma unroll
    for (int et = 0; et < 2; ++et)
      #pragma unroll
      for (int dt = 0; dt < 4; ++dt)
        #pragma unroll
        for (int q = 0; q < 4; ++q)
          red[(wid-2)*2080 + (16*et + 4*lg + q)*65 + 16*dt + l15] += acc2[et][dt][q];
  }
  __syncthreads();
  for (int i = threadIdx.x; i < EE*DD; i += 256){
    const int e = i >> 6, d = i & 63;
    atomicAdd(&hf[(size_t)b*EE*DD + i], red[e*65 + d] + red[2080 + e*65 + d]);
  }
}

// ---------------- K14: per-block ho preamble (ex-k3, LDS) + fused STGCN + hyper-combine ----------------
// REQUIRES xin != xout (launcher ping-pongs): reads x[t-1] rows cross-tile.
__global__ __launch_bounds__(256, 2)
void k14_fused(const float* __restrict__ x,
               const float* __restrict__ W1, const float* __restrict__ b1,
               const float* __restrict__ W2, const float* __restrict__ b2,
               const float* __restrict__ lng, const float* __restrict__ lnb,
               const unsigned short* __restrict__ assign_hi,
               const unsigned short* __restrict__ assign_lo,
               const float* __restrict__ hf, const float* __restrict__ em,
               const float* __restrict__ hg, const float* __restrict__ hb,
               float* __restrict__ xout)
{
  __shared__ float ems[EE*EE];
  __shared__ float hfs[EE*DD];
  __shared__ float hos[EE*DD];
  const int lane = threadIdx.x & 63;
  const int wid  = threadIdx.x >> 6;
  const int b    = blockIdx.x / CPB4;
  const int blk  = blockIdx.x % CPB4;
  const int l15  = lane & 15;
  const int lg   = lane >> 4;
  const int k0   = lg * 8;

  // ---- ho preamble (bit-identical math to former k3_edge) ----
  for (int i = threadIdx.x; i < EE*EE; i += 256) ems[i] = em[i];
  for (int i = threadIdx.x; i < EE*DD; i += 256) hfs[i] = hf[(size_t)b*EE*DD + i];
  __syncthreads();
  for (int i = threadIdx.x; i < EE*DD; i += 256){
    const int e = i >> 6, d = i & 63;
    float acc = 0.f;
    #pragma unroll
    for (int f = 0; f < EE; ++f) acc = fmaf(ems[e*EE+f], hfs[f*DD+d], acc);
    hos[i] = fmaxf(acc, 0.f) + hfs[e*DD+d];
  }
  __syncthreads();

  // ho fragments built from LDS (same values as former ho_hi/ho_lo load)
  short8 bwh[4], bwl[4];
  #pragma unroll
  for (int nt = 0; nt < 4; ++nt){
    float v[8];
    #pragma unroll
    for (int j = 0; j < 8; ++j)
      v[j] = hos[(8*lg + j)*DD + l15 + 16*nt];
    bwh[nt] = pack_hi8(v);
    bwl[nt] = pack_lo8(v, bwh[nt]);
  }

  // W fragments (k1 part)
  short8 bw[2][4][2];
  const float* Wm[2] = {W1, W2};
  #pragma unroll
  for (int m = 0; m < 2; ++m)
    #pragma unroll
    for (int nt = 0; nt < 4; ++nt)
      #pragma unroll
      for (int kc = 0; kc < 2; ++kc){
        const float* src = Wm[m] + (size_t)(16*nt + l15)*DD + 32*kc + k0;
        const float4 p0 = *reinterpret_cast<const float4*>(src);
        const float4 p1 = *reinterpret_cast<const float4*>(src + 4);
        int4v w;
        w.x = cvt2(p0.x, p0.y); w.y = cvt2(p0.z, p0.w);
        w.z = cvt2(p1.x, p1.y); w.w = cvt2(p1.z, p1.w);
        bw[m][nt][kc] = __builtin_bit_cast(short8, w);
      }

  float b1c[4], b2c[4], g1c[4], B1c[4], g2c[4], B2c[4];
  #pragma unroll
  for (int nt = 0; nt < 4; ++nt){
    b1c[nt] = b1[l15 + 16*nt];
    b2c[nt] = b2[l15 + 16*nt];
    g1c[nt] = lng[l15 + 16*nt];
    B1c[nt] = lnb[l15 + 16*nt];
    g2c[nt] = hg[l15 + 16*nt];
    B2c[nt] = hb[l15 + 16*nt];
  }

  const int tpb = MM / 16;                      // 768 tiles per batch; 3 tiles/wave at CPB4=64
  for (int tl = blk*4 + wid; tl < tpb; tl += CPB4*4){
    const size_t r0 = (size_t)b*MM + (size_t)tl*16;  // global row base
    const int t = (tl*16) >> 10;                // local frame index 0..11

    // ---- k1-part A-fragments ----
    const float* pc = x + (r0 + l15)*DD + k0;
    float4 a00 = *reinterpret_cast<const float4*>(pc);
    float4 a01 = *reinterpret_cast<const float4*>(pc + 4);
    float4 a10 = *reinterpret_cast<const float4*>(pc + 32);
    float4 a11 = *reinterpret_cast<const float4*>(pc + 36);
    if (t > 0){
      const float* pp = pc - (size_t)NN*DD;
      const float4 q00 = *reinterpret_cast<const float4*>(pp);
      const float4 q01 = *reinterpret_cast<const float4*>(pp + 4);
      const float4 q10 = *reinterpret_cast<const float4*>(pp + 32);
      const float4 q11 = *reinterpret_cast<const float4*>(pp + 36);
      a00.x = 0.5f*(a00.x+q00.x); a00.y = 0.5f*(a00.y+q00.y);
      a00.z = 0.5f*(a00.z+q00.z); a00.w = 0.5f*(a00.w+q00.w);
      a01.x = 0.5f*(a01.x+q01.x); a01.y = 0.5f*(a01.y+q01.y);
      a01.z = 0.5f*(a01.z+q01.z); a01.w = 0.5f*(a01.w+q01.w);
      a10.x = 0.5f*(a10.x+q10.x); a10.y = 0.5f*(a10.y+q10.y);
      a10.z = 0.5f*(a10.z+q10.z); a10.w = 0.5f*(a10.w+q10.w);
      a11.x = 0.5f*(a11.x+q11.x); a11.y = 0.5f*(a11.y+q11.y);
      a11.z = 0.5f*(a11.z+q11.z); a11.w = 0.5f*(a11.w+q11.w);
    } else {
      a00.x*=0.5f;a00.y*=0.5f;a00.z*=0.5f;a00.w*=0.5f;
      a01.x*=0.5f;a01.y*=0.5f;a01.z*=0.5f;a01.w*=0.5f;
      a10.x*=0.5f;a10.y*=0.5f;a10.z*=0.5f;a10.w*=0.5f;
      a11.x*=0.5f;a11.y*=0.5f;a11.z*=0.5f;a11.w*=0.5f;
    }
    // shared epilogue x loads (C-layout rows)
    float epi[4][4];
    #pragma unroll
    for (int q = 0; q < 4; ++q){
      const float* pr = x + (r0 + 4*lg + q)*DD + l15;
      #pragma unroll
      for (int nt = 0; nt < 4; ++nt) epi[q][nt] = pr[16*nt];
    }
    // k4-part A-fragments
    const short8 afh = *reinterpret_cast<const short8*>(assign_hi + (r0 + l15)*EE + 8*lg);
    const short8 afl = *reinterpret_cast<const short8*>(assign_lo + (r0 + l15)*EE + 8*lg);

    short8 af[2];
    {
      int4v w;
      w.x = cvt2(a00.x, a00.y); w.y = cvt2(a00.z, a00.w);
      w.z = cvt2(a01.x, a01.y); w.w = cvt2(a01.z, a01.w);
      af[0] = __builtin_bit_cast(short8, w);
      w.x = cvt2(a10.x, a10.y); w.y = cvt2(a10.z, a10.w);
      w.z = cvt2(a11.x, a11.y); w.w = cvt2(a11.z, a11.w);
      af[1] = __builtin_bit_cast(short8, w);
    }

    f32x4 acc1[2][4], acc4[4];
    #pragma unroll
    for (int m = 0; m < 2; ++m)
      #pragma unroll
      for (int nt = 0; nt < 4; ++nt) acc1[m][nt] = (f32x4){0.f,0.f,0.f,0.f};
    #pragma unroll
    for (int nt = 0; nt < 4; ++nt) acc4[nt] = (f32x4){0.f,0.f,0.f,0.f};

    #pragma unroll
    for (int kc = 0; kc < 2; ++kc){
      #pragma unroll
      for (int nt = 0; nt < 4; ++nt){
        acc1[0][nt] = __builtin_amdgcn_mfma_f32_16x16x32_bf16(af[kc], bw[0][nt][kc], acc1[0][nt], 0, 0, 0);
        acc1[1][nt] = __builtin_amdgcn_mfma_f32_16x16x32_bf16(af[kc], bw[1][nt][kc], acc1[1][nt], 0, 0, 0);
      }
    }
    #pragma unroll
    for (int nt = 0; nt < 4; ++nt){
      acc4[nt] = __builtin_amdgcn_mfma_f32_16x16x32_bf16(afh, bwh[nt], acc4[nt], 0, 0, 0);
      acc4[nt] = __builtin_amdgcn_mfma_f32_16x16x32_bf16(afh, bwl[nt], acc4[nt], 0, 0, 0);
      acc4[nt] = __builtin_amdgcn_mfma_f32_16x16x32_bf16(afl, bwh[nt], acc4[nt], 0, 0, 0);
    }

    // ---- dual epilogue: LN1 (stgcn) and LN2 (hyper), interleaved shfl chains ----
    #pragma unroll
    for (int q = 0; q < 4; ++q){
      const size_t row = r0 + 4*lg + q;
      float s1[4], s2[4];
      float rs1 = 0.f, rs2 = 0.f;
      #pragma unroll
      for (int nt = 0; nt < 4; ++nt){
        const float g1 = acc1[0][nt][q] + b1c[nt];
        const float g2 = acc1[1][nt][q] + b2c[nt];
        s1[nt] = fmaxf(g1*g2, 0.f) + g1 + epi[q][nt];
        rs1 += s1[nt];
        s2[nt] = fmaxf(acc4[nt][q], 0.f) + epi[q][nt];
        rs2 += s2[nt];
      }
      #pragma unroll
      for (int off = 8; off; off >>= 1){ rs1 += __shfl_xor(rs1, off); rs2 += __shfl_xor(rs2, off); }
      const float m1 = rs1 * (1.f/DD);
      const float m2 = rs2 * (1.f/DD);
      float d1[4], d2[4]; float v1 = 0.f, v2 = 0.f;
      #pragma unroll
      for (int nt = 0; nt < 4; ++nt){
        d1[nt] = s1[nt] - m1; v1 = fmaf(d1[nt], d1[nt], v1);
        d2[nt] = s2[nt] - m2; v2 = fmaf(d2[nt], d2[nt], v2);
      }
      #pragma unroll
      for (int off = 8; off; off >>= 1){ v1 += __shfl_xor(v1, off); v2 += __shfl_xor(v2, off); }
      const float i1 = rsqrtf(v1 * (1.f/DD) + LN_EPS);
      const float i2 = rsqrtf(v2 * (1.f/DD) + LN_EPS);
      #pragma unroll
      for (int nt = 0; nt < 4; ++nt){
        const float o1 = d1[nt]*i1*g1c[nt] + B1c[nt];
        const float o2 = d2[nt]*i2*g2c[nt] + B2c[nt];
        xout[row*DD + l15 + 16*nt] = 0.5f*(o1 + o2);
      }
    }
  }
}

extern "C" void kernel_launch(void* const* d_in, const int* in_sizes, int n_in,
                              void* d_out, int out_size, void* d_ws, size_t ws_size,
                              hipStream_t stream)
{
  (void)in_sizes; (void)n_in; (void)out_size; (void)ws_size;
  const float* x0  = (const float*)d_in[0];
  const float* W1  = (const float*)d_in[1];
  const float* b1  = (const float*)d_in[2];
  const float* W2  = (const float*)d_in[3];
  const float* b2  = (const float*)d_in[4];
  const float* lng = (const float*)d_in[5];
  const float* lnb = (const float*)d_in[6];
  const float* clf = (const float*)d_in[7];
  const float* em  = (const float*)d_in[8];
  const float* hg  = (const float*)d_in[9];
  const float* hb  = (const float*)d_in[10];
  float* out = (float*)d_out;

  // workspace: x ping f32 | hf f32 [BB][EE*DD] (128 KB) | assign hi/lo bf16
  float* ws_x = (float*)d_ws;
  float* hf   = ws_x + (size_t)ROWS*DD;
  unsigned short* assign_hi = (unsigned short*)(hf + (size_t)BB*EE*DD);
  unsigned short* assign_lo = assign_hi + (size_t)ROWS*EE;

  // ping-pong so xin != xout at EVERY depth (k14 reads t-1 rows cross-tile):
  // depth 0: x0 -> d_out ; depth 1: d_out -> ws_x ; depth 2: ws_x -> d_out (final)
  const float* xin_seq[3]  = { x0, out, ws_x };
  float*       xout_seq[3] = { out, ws_x, out };

  for (int i = 0; i < 3; ++i){
    const float* xin = xin_seq[i];
    float* xout = xout_seq[i];
    hipMemsetAsync(hf, 0, (size_t)BB*EE*DD*sizeof(float), stream);
    k2_hyper1<<<BB*CPB2N, 256, 0, stream>>>(xin, clf, assign_hi, assign_lo, hf);
    k14_fused<<<BB*CPB4, 256, 0, stream>>>(xin, W1 + i*DD*DD, b1 + i*DD,
                                           W2 + i*DD*DD, b2 + i*DD,
                                           lng + i*DD, lnb + i*DD,
                                           assign_hi, assign_lo, hf, em,
                                           hg, hb, xout);
  }
}